// Round 1
// baseline (464.520 us; speedup 1.0000x reference)
//
#include <hip/hip_runtime.h>
#include <cmath>

#define H_DIM 75
#define W_DIM 100
#define HW 7500
#define KSEL 2000
#define BATCH 8
#define CIN 512
#define FDIM 128

__device__ __forceinline__ unsigned int map_key(float f) {
  unsigned int u = __float_as_uint(f);
  return (u & 0x80000000u) ? ~u : (u | 0x80000000u);
}

// K1: per-batch top-K selection; bitonic sort finds exact Kth-largest key,
// then a packed (gt|eq) prefix scan emits selected indices in ascending order
// with lowest-index tie-breaking (matches lax.top_k + sort semantics).
__global__ __launch_bounds__(1024) void topk_kernel(
    const float* __restrict__ pred, int* __restrict__ idx_ws,
    float* __restrict__ out_idx)
{
  __shared__ unsigned int keys[8192];
  __shared__ unsigned int partials[1024];
  const int b = blockIdx.x;
  const int tid = threadIdx.x;
  const float* scores = pred + (size_t)b * 3 * HW;  // channel 0 of predict
  for (int i = tid; i < 8192; i += 1024)
    keys[i] = (i < HW) ? map_key(scores[i]) : 0u;   // pad with minimal key
  __syncthreads();
  for (int k = 2; k <= 8192; k <<= 1) {
    for (int j = k >> 1; j > 0; j >>= 1) {
      for (int i = tid; i < 8192; i += 1024) {
        int l = i ^ j;
        if (l > i) {
          unsigned int a = keys[i], c = keys[l];
          bool asc = ((i & k) == 0);
          if ((a > c) == asc) { keys[i] = c; keys[l] = a; }
        }
      }
      __syncthreads();
    }
  }
  unsigned int thresh = keys[8192 - KSEL];  // Kth largest (ascending sort)
  __syncthreads();

  unsigned int local[8];
  unsigned int sum = 0;
  for (int e = 0; e < 8; ++e) {
    int i = tid * 8 + e;
    unsigned int p = 0;
    if (i < HW) {
      unsigned int ky = map_key(scores[i]);
      if (ky > thresh) p = 1u;
      else if (ky == thresh) p = (1u << 16);
    }
    local[e] = p; sum += p;
  }
  partials[tid] = sum;
  __syncthreads();
  for (int off = 1; off < 1024; off <<= 1) {
    unsigned int v = partials[tid];
    unsigned int add = (tid >= off) ? partials[tid - off] : 0u;
    __syncthreads();
    partials[tid] = v + add;
    __syncthreads();
  }
  unsigned int total = partials[1023];
  unsigned int run = (tid > 0) ? partials[tid - 1] : 0u;
  unsigned int ties = (unsigned int)KSEL - (total & 0xFFFFu);
  for (int e = 0; e < 8; ++e) {
    int i = tid * 8 + e;
    unsigned int p = local[e];
    unsigned int gt_pref = run & 0xFFFFu;
    unsigned int eq_pref = run >> 16;
    bool sel = (p & 1u) || (((p >> 16) != 0u) && eq_pref < ties);
    if (sel) {
      unsigned int pos = gt_pref + (eq_pref < ties ? eq_pref : ties);
      idx_ws[b * KSEL + pos] = i;
      out_idx[b * KSEL + pos] = (float)i;
    }
    run += p;
  }
}

// K2: neighbor lists. Ascending idx => neighbors live in window [q-101, q+101].
// Max 9 neighbors (3x3 box of distinct cells), includes self.
__global__ __launch_bounds__(256) void nbr_kernel(
    const int* __restrict__ idx_ws, unsigned short* __restrict__ nbr,
    unsigned char* __restrict__ cnt)
{
  __shared__ int s_idx[KSEL];
  const int b = blockIdx.x, tid = threadIdx.x;
  for (int i = tid; i < KSEL; i += 256) s_idx[i] = idx_ws[b * KSEL + i];
  __syncthreads();
  for (int i = tid; i < KSEL; i += 256) {
    int q = s_idx[i];
    int py = q / W_DIM, px = q % W_DIM;
    int target = q - (W_DIM + 1);
    int lo = 0, hi = KSEL;
    while (lo < hi) { int mid = (lo + hi) >> 1; if (s_idx[mid] < target) lo = mid + 1; else hi = mid; }
    int c = 0;
    int hiq = q + W_DIM + 1;
    for (int j = lo; j < KSEL; ++j) {
      int qj = s_idx[j];
      if (qj > hiq) break;
      int dy = qj / W_DIM - py;
      int dx = qj % W_DIM - px;
      if (dy >= -1 && dy <= 1 && dx >= -1 && dx <= 1 && c < 9)
        nbr[(size_t)(b * KSEL + i) * 9 + (c++)] = (unsigned short)j;
    }
    cnt[b * KSEL + i] = (unsigned char)c;
  }
}

// K3/K5: OUT[2000x128] = IN[2000xCDIM] @ W[CDIMx128], per batch.
// GATHER: IN row n = clip(feature[b, :, q%75, q/75], 0, 6)  (reference's index quirk).
// 32-row x 128-col block tile, 32-deep c-chunks, 4x4 register tile per thread.
template<int CDIM, bool GATHER>
__global__ __launch_bounds__(256) void gemm_kernel(
    const float* __restrict__ in, const float* __restrict__ wmat,
    const int* __restrict__ idx_ws, float* __restrict__ out)
{
  __shared__ __align__(16) float a_lds[32][36];   // [c][n], pad 36 (mult of 4 for b128)
  __shared__ __align__(16) float w_lds[32][128];  // [c][f]
  __shared__ int s_off[32];
  const int b = blockIdx.y;
  const int n0 = blockIdx.x * 32;
  const int tid = threadIdx.x;
  if (GATHER) {
    if (tid < 32) {
      int row = n0 + tid;
      int off = -1;
      if (row < KSEL) {
        int q = idx_ws[b * KSEL + row];
        off = (q % H_DIM) * W_DIM + q / H_DIM;   // h'=q%75, w'=q/75
      }
      s_off[tid] = off;
    }
    __syncthreads();
  }
  const int tf = tid & 31, tr = tid >> 5;
  float acc[4][4] = {{0.f}};
  const float* fb = in + (GATHER ? (size_t)b * CIN * HW : (size_t)b * KSEL * FDIM);
  for (int cc = 0; cc < CDIM; cc += 32) {
    for (int e = tid; e < 32 * 128; e += 256) {
      int c = e >> 7, f = e & 127;
      w_lds[c][f] = wmat[(cc + c) * 128 + f];
    }
    if (GATHER) {
      for (int e = tid; e < 1024; e += 256) {
        int c = e >> 5, n = e & 31;
        int off = s_off[n];
        float v = 0.f;
        if (off >= 0) {
          v = fb[(size_t)(cc + c) * HW + off];
          v = fminf(fmaxf(v, 0.f), 6.f);
        }
        a_lds[c][n] = v;
      }
    } else {
      for (int e = tid; e < 1024; e += 256) {
        int n = e >> 5, c = e & 31;
        int row = n0 + n;
        a_lds[c][n] = (row < KSEL) ? fb[(size_t)row * FDIM + cc + c] : 0.f;
      }
    }
    __syncthreads();
    #pragma unroll
    for (int c = 0; c < 32; ++c) {
      float4 av = *(const float4*)&a_lds[c][tr * 4];
      float4 wv = *(const float4*)&w_lds[c][tf * 4];
      acc[0][0] += av.x * wv.x; acc[0][1] += av.x * wv.y; acc[0][2] += av.x * wv.z; acc[0][3] += av.x * wv.w;
      acc[1][0] += av.y * wv.x; acc[1][1] += av.y * wv.y; acc[1][2] += av.y * wv.z; acc[1][3] += av.y * wv.w;
      acc[2][0] += av.z * wv.x; acc[2][1] += av.z * wv.y; acc[2][2] += av.z * wv.z; acc[2][3] += av.z * wv.w;
      acc[3][0] += av.w * wv.x; acc[3][1] += av.w * wv.y; acc[3][2] += av.w * wv.z; acc[3][3] += av.w * wv.w;
    }
    __syncthreads();
  }
  for (int r = 0; r < 4; ++r) {
    int row = n0 + tr * 4 + r;
    if (row < KSEL) {
      float4 v = make_float4(acc[r][0], acc[r][1], acc[r][2], acc[r][3]);
      *(float4*)&out[((size_t)(b * KSEL + row)) * FDIM + tf * 4] = v;
    }
  }
}

// K4: x1[i] = b1[i] + sum_{j in nbr(i)} G[j]
__global__ __launch_bounds__(128) void x1_kernel(
    const float* __restrict__ G, const float* __restrict__ b1,
    const unsigned short* __restrict__ nbr, const unsigned char* __restrict__ cnt,
    float* __restrict__ x1)
{
  const int bi = blockIdx.x;
  const int i = bi % KSEL;
  const int base = bi - i;
  const int f = threadIdx.x;
  float acc = b1[i * FDIM + f];
  const int c = cnt[bi];
  const unsigned short* nb = nbr + (size_t)bi * 9;
  for (int t = 0; t < c; ++t)
    acc += G[(size_t)(base + nb[t]) * FDIM + f];
  x1[(size_t)bi * FDIM + f] = acc;
}

// K6: out[i] = tanh(b2[i] + x1[i] + sum_{j in nbr(i)} H[j])
__global__ __launch_bounds__(128) void out_kernel(
    const float* __restrict__ Hm, const float* __restrict__ x1,
    const float* __restrict__ b2,
    const unsigned short* __restrict__ nbr, const unsigned char* __restrict__ cnt,
    float* __restrict__ out)
{
  const int bi = blockIdx.x;
  const int i = bi % KSEL;
  const int base = bi - i;
  const int f = threadIdx.x;
  float acc = b2[i * FDIM + f] + x1[(size_t)bi * FDIM + f];
  const int c = cnt[bi];
  const unsigned short* nb = nbr + (size_t)bi * 9;
  for (int t = 0; t < c; ++t)
    acc += Hm[(size_t)(base + nb[t]) * FDIM + f];
  out[(size_t)bi * FDIM + f] = tanhf(acc);
}

extern "C" void kernel_launch(void* const* d_in, const int* in_sizes, int n_in,
                              void* d_out, int out_size, void* d_ws, size_t ws_size,
                              hipStream_t stream) {
  const float* feat = (const float*)d_in[0];
  const float* pred = (const float*)d_in[1];
  const float* w1   = (const float*)d_in[2];
  const float* b1   = (const float*)d_in[3];
  const float* w2   = (const float*)d_in[4];
  const float* b2   = (const float*)d_in[5];
  float* out0 = (float*)d_out;                              // (8,2000,128) fp32
  float* out_idx = out0 + (size_t)BATCH * KSEL * FDIM;      // (8,2000) as fp32

  // workspace layout (all offsets 128B-aligned)
  char* ws = (char*)d_ws;
  int*            idx_ws = (int*)(ws + 0);                  // 64000 B
  unsigned short* nbr    = (unsigned short*)(ws + 64256);   // 288000 B
  unsigned char*  cnt    = (unsigned char*)(ws + 352512);   // 16000 B
  float*          G      = (float*)(ws + 368640);           // 8.192 MB
  float*          x1     = (float*)(ws + 8560640);          // 8.192 MB
  float*          Hm     = (float*)(ws + 16752640);         // 8.192 MB

  topk_kernel<<<BATCH, 1024, 0, stream>>>(pred, idx_ws, out_idx);
  nbr_kernel<<<BATCH, 256, 0, stream>>>(idx_ws, nbr, cnt);
  gemm_kernel<CIN, true><<<dim3(63, BATCH), 256, 0, stream>>>(feat, w1, idx_ws, G);
  x1_kernel<<<BATCH * KSEL, 128, 0, stream>>>(G, b1, nbr, cnt, x1);
  gemm_kernel<FDIM, false><<<dim3(63, BATCH), 256, 0, stream>>>(x1, w2, idx_ws, Hm);
  out_kernel<<<BATCH * KSEL, 128, 0, stream>>>(Hm, x1, b2, nbr, cnt, out0);
}

// Round 2
// 404.153 us; speedup vs baseline: 1.1494x; 1.1494x over previous
//
#include <hip/hip_runtime.h>
#include <cmath>

#define H_DIM 75
#define W_DIM 100
#define HW 7500
#define KSEL 2000
#define BATCH 8
#define CIN 512
#define FDIM 128

__device__ __forceinline__ unsigned int map_key(float f) {
  unsigned int u = __float_as_uint(f);
  return (u & 0x80000000u) ? ~u : (u | 0x80000000u);
}

// K1: per-batch top-K via 4-round radix select (exact Kth-largest key), then
// packed (gt|eq) prefix scan emits selected indices in ascending order with
// lowest-index tie-breaking (matches lax.top_k + sort semantics).
__global__ __launch_bounds__(1024) void topk_kernel(
    const float* __restrict__ pred, int* __restrict__ idx_ws,
    int* __restrict__ off_ws, float* __restrict__ out_idx)
{
  __shared__ unsigned int keys[HW];
  __shared__ unsigned int hist[256];
  __shared__ unsigned int partials[1024];
  __shared__ unsigned int s_prefix, s_kth;
  const int b = blockIdx.x;
  const int tid = threadIdx.x;
  const float* scores = pred + (size_t)b * 3 * HW;  // channel 0 of predict
  for (int i = tid; i < HW; i += 1024) keys[i] = map_key(scores[i]);
  if (tid == 0) { s_prefix = 0u; s_kth = KSEL; }
  __syncthreads();

  // radix select, MSB-first, 8 bits per round
  for (int shift = 24; shift >= 0; shift -= 8) {
    for (int i = tid; i < 256; i += 1024) hist[i] = 0u;
    __syncthreads();
    unsigned int pref = s_prefix;
    unsigned int maskhi = (shift == 24) ? 0u : (0xFFFFFFFFu << (shift + 8));
    for (int i = tid; i < HW; i += 1024) {
      unsigned int k = keys[i];
      if ((k & maskhi) == pref) atomicAdd(&hist[(k >> shift) & 0xFFu], 1u);
    }
    __syncthreads();
    unsigned int kth = s_kth;  // all threads read before any scan barrier
    // suffix sum hist[i] = sum_{j>=i} hist[j]  (Hillis-Steele, reversed)
    for (int off = 1; off < 256; off <<= 1) {
      unsigned int v = 0, add = 0;
      if (tid < 256) { v = hist[tid]; add = (tid + off < 256) ? hist[tid + off] : 0u; }
      __syncthreads();
      if (tid < 256) hist[tid] = v + add;
      __syncthreads();
    }
    if (tid < 256) {
      unsigned int s = hist[tid];
      unsigned int s_above = (tid < 255) ? hist[tid + 1] : 0u;
      if (s >= kth && s_above < kth) {  // exactly one thread matches
        s_prefix = pref | ((unsigned int)tid << shift);
        s_kth = kth - s_above;
      }
    }
    __syncthreads();
  }
  unsigned int thresh = s_prefix;
  __syncthreads();

  // selection scan: gt in low half, eq in high half, packed
  unsigned int local[8];
  unsigned int sum = 0;
  for (int e = 0; e < 8; ++e) {
    int i = tid * 8 + e;
    unsigned int p = 0;
    if (i < HW) {
      unsigned int ky = keys[i];
      if (ky > thresh) p = 1u;
      else if (ky == thresh) p = (1u << 16);
    }
    local[e] = p; sum += p;
  }
  partials[tid] = sum;
  __syncthreads();
  for (int off = 1; off < 1024; off <<= 1) {
    unsigned int v = partials[tid];
    unsigned int add = (tid >= off) ? partials[tid - off] : 0u;
    __syncthreads();
    partials[tid] = v + add;
    __syncthreads();
  }
  unsigned int total = partials[1023];
  unsigned int run = (tid > 0) ? partials[tid - 1] : 0u;
  unsigned int ties = (unsigned int)KSEL - (total & 0xFFFFu);
  for (int e = 0; e < 8; ++e) {
    int i = tid * 8 + e;
    unsigned int p = local[e];
    unsigned int gt_pref = run & 0xFFFFu;
    unsigned int eq_pref = run >> 16;
    bool sel = (p & 1u) || (((p >> 16) != 0u) && eq_pref < ties);
    if (sel) {
      unsigned int pos = gt_pref + (eq_pref < ties ? eq_pref : ties);
      idx_ws[b * KSEL + pos] = i;
      off_ws[b * KSEL + pos] = (i % H_DIM) * W_DIM + i / H_DIM;  // gather offset quirk
      out_idx[b * KSEL + pos] = (float)i;
    }
    run += p;
  }
}

// K2: neighbor lists. Ascending idx => neighbors live in window [q-101, q+101].
__global__ __launch_bounds__(256) void nbr_kernel(
    const int* __restrict__ idx_ws, unsigned short* __restrict__ nbr,
    unsigned char* __restrict__ cnt)
{
  __shared__ int s_idx[KSEL];
  const int b = blockIdx.x, tid = threadIdx.x;
  for (int i = tid; i < KSEL; i += 256) s_idx[i] = idx_ws[b * KSEL + i];
  __syncthreads();
  for (int i = tid; i < KSEL; i += 256) {
    int q = s_idx[i];
    int py = q / W_DIM, px = q % W_DIM;
    int target = q - (W_DIM + 1);
    int lo = 0, hi = KSEL;
    while (lo < hi) { int mid = (lo + hi) >> 1; if (s_idx[mid] < target) lo = mid + 1; else hi = mid; }
    int c = 0;
    int hiq = q + W_DIM + 1;
    for (int j = lo; j < KSEL; ++j) {
      int qj = s_idx[j];
      if (qj > hiq) break;
      int dy = qj / W_DIM - py;
      int dx = qj % W_DIM - px;
      if (dy >= -1 && dy <= 1 && dx >= -1 && dx <= 1 && c < 9)
        nbr[(size_t)(b * KSEL + i) * 9 + (c++)] = (unsigned short)j;
    }
    cnt[b * KSEL + i] = (unsigned char)c;
  }
}

// K2b: gather+clip+transpose. Each block owns 8 full c-planes -> every feature
// cache line fetched exactly once; writes NFT[b][c][n] densely ([c][n] layout
// matches GEMM1's LDS tile layout).
__global__ __launch_bounds__(256) void gather_kernel(
    const float* __restrict__ feat, const int* __restrict__ off_ws,
    float* __restrict__ NFT)
{
  __shared__ int s_off[KSEL];
  const int b = blockIdx.y;
  const int c0 = blockIdx.x * 8;
  const int tid = threadIdx.x;
  for (int i = tid; i < KSEL; i += 256) s_off[i] = off_ws[b * KSEL + i];
  __syncthreads();
  const float* fb = feat + (size_t)b * CIN * HW;
  float* nb = NFT + (size_t)b * CIN * KSEL;
  #pragma unroll
  for (int cc = 0; cc < 8; ++cc) {
    const float* plane = fb + (size_t)(c0 + cc) * HW;
    float* orow = nb + (size_t)(c0 + cc) * KSEL;
    #pragma unroll 4
    for (int n = tid; n < KSEL; n += 256) {
      float v = plane[s_off[n]];
      orow[n] = fminf(fmaxf(v, 0.f), 6.f);
    }
  }
}

// K3/K5: OUT[2000x128] = IN[2000xCDIM] @ W[CDIMx128], per batch.
// CMAJOR: IN is NFT [c][n] (clip already applied). else IN is row-major [n][f].
template<int CDIM, bool CMAJOR>
__global__ __launch_bounds__(256) void gemm_kernel(
    const float* __restrict__ in, const float* __restrict__ wmat,
    float* __restrict__ out)
{
  __shared__ __align__(16) float a_lds[32][36];   // [c][n], pad 36
  __shared__ __align__(16) float w_lds[32][128];  // [c][f]
  const int b = blockIdx.y;
  const int n0 = blockIdx.x * 32;
  const int tid = threadIdx.x;
  const int tf = tid & 31, tr = tid >> 5;
  float acc[4][4] = {{0.f}};
  const float* fb = in + (CMAJOR ? (size_t)b * CIN * KSEL : (size_t)b * KSEL * FDIM);
  for (int cc = 0; cc < CDIM; cc += 32) {
    for (int e = tid; e < 32 * 128; e += 256) {
      int c = e >> 7, f = e & 127;
      w_lds[c][f] = wmat[(cc + c) * 128 + f];
    }
    if (CMAJOR) {
      for (int e = tid; e < 1024; e += 256) {
        int c = e >> 5, n = e & 31;
        int row = n0 + n;
        a_lds[c][n] = (row < KSEL) ? fb[(size_t)(cc + c) * KSEL + row] : 0.f;
      }
    } else {
      for (int e = tid; e < 1024; e += 256) {
        int n = e >> 5, c = e & 31;
        int row = n0 + n;
        a_lds[c][n] = (row < KSEL) ? fb[(size_t)row * FDIM + cc + c] : 0.f;
      }
    }
    __syncthreads();
    #pragma unroll
    for (int c = 0; c < 32; ++c) {
      float4 av = *(const float4*)&a_lds[c][tr * 4];
      float4 wv = *(const float4*)&w_lds[c][tf * 4];
      acc[0][0] += av.x * wv.x; acc[0][1] += av.x * wv.y; acc[0][2] += av.x * wv.z; acc[0][3] += av.x * wv.w;
      acc[1][0] += av.y * wv.x; acc[1][1] += av.y * wv.y; acc[1][2] += av.y * wv.z; acc[1][3] += av.y * wv.w;
      acc[2][0] += av.z * wv.x; acc[2][1] += av.z * wv.y; acc[2][2] += av.z * wv.z; acc[2][3] += av.z * wv.w;
      acc[3][0] += av.w * wv.x; acc[3][1] += av.w * wv.y; acc[3][2] += av.w * wv.z; acc[3][3] += av.w * wv.w;
    }
    __syncthreads();
  }
  for (int r = 0; r < 4; ++r) {
    int row = n0 + tr * 4 + r;
    if (row < KSEL) {
      float4 v = make_float4(acc[r][0], acc[r][1], acc[r][2], acc[r][3]);
      *(float4*)&out[((size_t)(b * KSEL + row)) * FDIM + tf * 4] = v;
    }
  }
}

// K4: x1[i] = b1[i] + sum_{j in nbr(i)} G[j]
__global__ __launch_bounds__(128) void x1_kernel(
    const float* __restrict__ G, const float* __restrict__ b1,
    const unsigned short* __restrict__ nbr, const unsigned char* __restrict__ cnt,
    float* __restrict__ x1)
{
  const int bi = blockIdx.x;
  const int i = bi % KSEL;
  const int base = bi - i;
  const int f = threadIdx.x;
  float acc = b1[i * FDIM + f];
  const int c = cnt[bi];
  const unsigned short* nb = nbr + (size_t)bi * 9;
  for (int t = 0; t < c; ++t)
    acc += G[(size_t)(base + nb[t]) * FDIM + f];
  x1[(size_t)bi * FDIM + f] = acc;
}

// K6: out[i] = tanh(b2[i] + x1[i] + sum_{j in nbr(i)} H[j])
__global__ __launch_bounds__(128) void out_kernel(
    const float* __restrict__ Hm, const float* __restrict__ x1,
    const float* __restrict__ b2,
    const unsigned short* __restrict__ nbr, const unsigned char* __restrict__ cnt,
    float* __restrict__ out)
{
  const int bi = blockIdx.x;
  const int i = bi % KSEL;
  const int base = bi - i;
  const int f = threadIdx.x;
  float acc = b2[i * FDIM + f] + x1[(size_t)bi * FDIM + f];
  const int c = cnt[bi];
  const unsigned short* nb = nbr + (size_t)bi * 9;
  for (int t = 0; t < c; ++t)
    acc += Hm[(size_t)(base + nb[t]) * FDIM + f];
  out[(size_t)bi * FDIM + f] = tanhf(acc);
}

extern "C" void kernel_launch(void* const* d_in, const int* in_sizes, int n_in,
                              void* d_out, int out_size, void* d_ws, size_t ws_size,
                              hipStream_t stream) {
  const float* feat = (const float*)d_in[0];
  const float* pred = (const float*)d_in[1];
  const float* w1   = (const float*)d_in[2];
  const float* b1   = (const float*)d_in[3];
  const float* w2   = (const float*)d_in[4];
  const float* b2   = (const float*)d_in[5];
  float* out0 = (float*)d_out;                              // (8,2000,128) fp32
  float* out_idx = out0 + (size_t)BATCH * KSEL * FDIM;      // (8,2000) as fp32

  // workspace layout (256B-aligned). NFT (32.768 MB) is dead after gemm1, so
  // x1/Hm overlay it.
  char* ws = (char*)d_ws;
  int*            idx_ws = (int*)(ws + 0);                  //  64000 B
  int*            off_ws = (int*)(ws + 64256);              //  64000 B
  unsigned short* nbr    = (unsigned short*)(ws + 128512);  // 288000 B
  unsigned char*  cnt    = (unsigned char*)(ws + 416512);   //  16000 B
  float*          G      = (float*)(ws + 432640);           // 8.192 MB
  char*           R      = ws + 8624640;                    // 32.768 MB region
  float*          NFT    = (float*)R;                       // gemm1 input
  float*          x1     = (float*)R;                       // after gemm1
  float*          Hm     = (float*)(R + 8388608);           // after gemm1

  topk_kernel<<<BATCH, 1024, 0, stream>>>(pred, idx_ws, off_ws, out_idx);
  nbr_kernel<<<BATCH, 256, 0, stream>>>(idx_ws, nbr, cnt);
  gather_kernel<<<dim3(CIN / 8, BATCH), 256, 0, stream>>>(feat, off_ws, NFT);
  gemm_kernel<CIN, true><<<dim3(63, BATCH), 256, 0, stream>>>(NFT, w1, G);
  x1_kernel<<<BATCH * KSEL, 128, 0, stream>>>(G, b1, nbr, cnt, x1);
  gemm_kernel<FDIM, false><<<dim3(63, BATCH), 256, 0, stream>>>(x1, w2, Hm);
  out_kernel<<<BATCH * KSEL, 128, 0, stream>>>(Hm, x1, b2, nbr, cnt, out0);
}

// Round 3
// 336.238 us; speedup vs baseline: 1.3815x; 1.2020x over previous
//
#include <hip/hip_runtime.h>
#include <cmath>

#define H_DIM 75
#define W_DIM 100
#define HW 7500
#define KSEL 2000
#define BATCH 8
#define CIN 512
#define FDIM 128

__device__ __forceinline__ unsigned int map_key(float f) {
  unsigned int u = __float_as_uint(f);
  return (u & 0x80000000u) ? ~u : (u | 0x80000000u);
}

// K1: per-batch top-K via 4-round radix select (exact Kth-largest key), then
// packed (gt|eq) prefix scan emits selected indices in ascending order with
// lowest-index tie-breaking (matches lax.top_k + sort semantics).
__global__ __launch_bounds__(1024) void topk_kernel(
    const float* __restrict__ pred, int* __restrict__ idx_ws,
    int* __restrict__ off_ws, float* __restrict__ out_idx)
{
  __shared__ unsigned int keys[HW];
  __shared__ unsigned int hist[256];
  __shared__ unsigned int partials[1024];
  __shared__ unsigned int s_prefix, s_kth;
  const int b = blockIdx.x;
  const int tid = threadIdx.x;
  const float* scores = pred + (size_t)b * 3 * HW;  // channel 0 of predict
  for (int i = tid; i < HW; i += 1024) keys[i] = map_key(scores[i]);
  if (tid == 0) { s_prefix = 0u; s_kth = KSEL; }
  __syncthreads();

  // radix select, MSB-first, 8 bits per round
  for (int shift = 24; shift >= 0; shift -= 8) {
    for (int i = tid; i < 256; i += 1024) hist[i] = 0u;
    __syncthreads();
    unsigned int pref = s_prefix;
    unsigned int maskhi = (shift == 24) ? 0u : (0xFFFFFFFFu << (shift + 8));
    for (int i = tid; i < HW; i += 1024) {
      unsigned int k = keys[i];
      if ((k & maskhi) == pref) atomicAdd(&hist[(k >> shift) & 0xFFu], 1u);
    }
    __syncthreads();
    unsigned int kth = s_kth;  // all threads read before any scan barrier
    // suffix sum hist[i] = sum_{j>=i} hist[j]  (Hillis-Steele, reversed)
    for (int off = 1; off < 256; off <<= 1) {
      unsigned int v = 0, add = 0;
      if (tid < 256) { v = hist[tid]; add = (tid + off < 256) ? hist[tid + off] : 0u; }
      __syncthreads();
      if (tid < 256) hist[tid] = v + add;
      __syncthreads();
    }
    if (tid < 256) {
      unsigned int s = hist[tid];
      unsigned int s_above = (tid < 255) ? hist[tid + 1] : 0u;
      if (s >= kth && s_above < kth) {  // exactly one thread matches
        s_prefix = pref | ((unsigned int)tid << shift);
        s_kth = kth - s_above;
      }
    }
    __syncthreads();
  }
  unsigned int thresh = s_prefix;
  __syncthreads();

  // selection scan: gt in low half, eq in high half, packed
  unsigned int local[8];
  unsigned int sum = 0;
  for (int e = 0; e < 8; ++e) {
    int i = tid * 8 + e;
    unsigned int p = 0;
    if (i < HW) {
      unsigned int ky = keys[i];
      if (ky > thresh) p = 1u;
      else if (ky == thresh) p = (1u << 16);
    }
    local[e] = p; sum += p;
  }
  partials[tid] = sum;
  __syncthreads();
  for (int off = 1; off < 1024; off <<= 1) {
    unsigned int v = partials[tid];
    unsigned int add = (tid >= off) ? partials[tid - off] : 0u;
    __syncthreads();
    partials[tid] = v + add;
    __syncthreads();
  }
  unsigned int total = partials[1023];
  unsigned int run = (tid > 0) ? partials[tid - 1] : 0u;
  unsigned int ties = (unsigned int)KSEL - (total & 0xFFFFu);
  for (int e = 0; e < 8; ++e) {
    int i = tid * 8 + e;
    unsigned int p = local[e];
    unsigned int gt_pref = run & 0xFFFFu;
    unsigned int eq_pref = run >> 16;
    bool sel = (p & 1u) || (((p >> 16) != 0u) && eq_pref < ties);
    if (sel) {
      unsigned int pos = gt_pref + (eq_pref < ties ? eq_pref : ties);
      idx_ws[b * KSEL + pos] = i;
      off_ws[b * KSEL + pos] = (i % H_DIM) * W_DIM + i / H_DIM;  // gather offset quirk
      out_idx[b * KSEL + pos] = (float)i;
    }
    run += p;
  }
}

// K2: neighbor lists via inverse grid map. pos_of[cell] -> selected position
// or -1; each node probes its <=9 neighbor cells with independent LDS loads.
// (dy,dx) lexicographic scan == ascending-q order, matching sorted-idx order.
__global__ __launch_bounds__(256) void nbr_kernel(
    const int* __restrict__ idx_ws, unsigned short* __restrict__ nbr,
    unsigned char* __restrict__ cnt)
{
  __shared__ short pos_of[HW];   // 15 KB
  __shared__ int s_idx[KSEL];    //  8 KB
  const int b = blockIdx.x, tid = threadIdx.x;
  for (int i = tid; i < HW; i += 256) pos_of[i] = -1;
  __syncthreads();
  for (int i = tid; i < KSEL; i += 256) {
    int q = idx_ws[b * KSEL + i];
    s_idx[i] = q;
    pos_of[q] = (short)i;
  }
  __syncthreads();
  for (int i = tid; i < KSEL; i += 256) {
    int q = s_idx[i];
    int py = q / W_DIM, px = q % W_DIM;
    int c = 0;
    #pragma unroll
    for (int dy = -1; dy <= 1; ++dy) {
      int y = py + dy;
      if ((unsigned)y >= (unsigned)H_DIM) continue;  // py in [0,75)
      #pragma unroll
      for (int dx = -1; dx <= 1; ++dx) {
        int x = px + dx;
        if ((unsigned)x >= (unsigned)W_DIM) continue;
        short p = pos_of[y * W_DIM + x];
        if (p >= 0) nbr[(size_t)(b * KSEL + i) * 9 + (c++)] = (unsigned short)p;
      }
    }
    cnt[b * KSEL + i] = (unsigned char)c;
  }
}

// K2b: gather+clip+transpose. Each block owns 8 full c-planes -> every feature
// cache line fetched exactly once; writes NFT[b][c][n] densely ([c][n] layout
// matches GEMM1's LDS tile layout).
__global__ __launch_bounds__(256) void gather_kernel(
    const float* __restrict__ feat, const int* __restrict__ off_ws,
    float* __restrict__ NFT)
{
  __shared__ int s_off[KSEL];
  const int b = blockIdx.y;
  const int c0 = blockIdx.x * 8;
  const int tid = threadIdx.x;
  for (int i = tid; i < KSEL; i += 256) s_off[i] = off_ws[b * KSEL + i];
  __syncthreads();
  const float* fb = feat + (size_t)b * CIN * HW;
  float* nb = NFT + (size_t)b * CIN * KSEL;
  #pragma unroll
  for (int cc = 0; cc < 8; ++cc) {
    const float* plane = fb + (size_t)(c0 + cc) * HW;
    float* orow = nb + (size_t)(c0 + cc) * KSEL;
    #pragma unroll 4
    for (int n = tid; n < KSEL; n += 256) {
      float v = plane[s_off[n]];
      orow[n] = fminf(fmaxf(v, 0.f), 6.f);
    }
  }
}

// K3/K5: OUT[2000x128] = IN[2000xCDIM] @ W[CDIMx128], per batch.
// CMAJOR: IN is NFT [c][n] (clip already applied). else IN is row-major [n][f].
template<int CDIM, bool CMAJOR>
__global__ __launch_bounds__(256) void gemm_kernel(
    const float* __restrict__ in, const float* __restrict__ wmat,
    float* __restrict__ out)
{
  __shared__ __align__(16) float a_lds[32][36];   // [c][n], pad 36
  __shared__ __align__(16) float w_lds[32][128];  // [c][f]
  const int b = blockIdx.y;
  const int n0 = blockIdx.x * 32;
  const int tid = threadIdx.x;
  const int tf = tid & 31, tr = tid >> 5;
  float acc[4][4] = {{0.f}};
  const float* fb = in + (CMAJOR ? (size_t)b * CIN * KSEL : (size_t)b * KSEL * FDIM);
  for (int cc = 0; cc < CDIM; cc += 32) {
    for (int e = tid; e < 32 * 128; e += 256) {
      int c = e >> 7, f = e & 127;
      w_lds[c][f] = wmat[(cc + c) * 128 + f];
    }
    if (CMAJOR) {
      for (int e = tid; e < 1024; e += 256) {
        int c = e >> 5, n = e & 31;
        int row = n0 + n;
        a_lds[c][n] = (row < KSEL) ? fb[(size_t)(cc + c) * KSEL + row] : 0.f;
      }
    } else {
      for (int e = tid; e < 1024; e += 256) {
        int n = e >> 5, c = e & 31;
        int row = n0 + n;
        a_lds[c][n] = (row < KSEL) ? fb[(size_t)row * FDIM + cc + c] : 0.f;
      }
    }
    __syncthreads();
    #pragma unroll
    for (int c = 0; c < 32; ++c) {
      float4 av = *(const float4*)&a_lds[c][tr * 4];
      float4 wv = *(const float4*)&w_lds[c][tf * 4];
      acc[0][0] += av.x * wv.x; acc[0][1] += av.x * wv.y; acc[0][2] += av.x * wv.z; acc[0][3] += av.x * wv.w;
      acc[1][0] += av.y * wv.x; acc[1][1] += av.y * wv.y; acc[1][2] += av.y * wv.z; acc[1][3] += av.y * wv.w;
      acc[2][0] += av.z * wv.x; acc[2][1] += av.z * wv.y; acc[2][2] += av.z * wv.z; acc[2][3] += av.z * wv.w;
      acc[3][0] += av.w * wv.x; acc[3][1] += av.w * wv.y; acc[3][2] += av.w * wv.z; acc[3][3] += av.w * wv.w;
    }
    __syncthreads();
  }
  for (int r = 0; r < 4; ++r) {
    int row = n0 + tr * 4 + r;
    if (row < KSEL) {
      float4 v = make_float4(acc[r][0], acc[r][1], acc[r][2], acc[r][3]);
      *(float4*)&out[((size_t)(b * KSEL + row)) * FDIM + tf * 4] = v;
    }
  }
}

// K4: x1[i] = b1[i] + sum_{j in nbr(i)} G[j]
__global__ __launch_bounds__(128) void x1_kernel(
    const float* __restrict__ G, const float* __restrict__ b1,
    const unsigned short* __restrict__ nbr, const unsigned char* __restrict__ cnt,
    float* __restrict__ x1)
{
  const int bi = blockIdx.x;
  const int i = bi % KSEL;
  const int base = bi - i;
  const int f = threadIdx.x;
  float acc = b1[i * FDIM + f];
  const int c = cnt[bi];
  const unsigned short* nb = nbr + (size_t)bi * 9;
  for (int t = 0; t < c; ++t)
    acc += G[(size_t)(base + nb[t]) * FDIM + f];
  x1[(size_t)bi * FDIM + f] = acc;
}

// K6: out[i] = tanh(b2[i] + x1[i] + sum_{j in nbr(i)} H[j])
__global__ __launch_bounds__(128) void out_kernel(
    const float* __restrict__ Hm, const float* __restrict__ x1,
    const float* __restrict__ b2,
    const unsigned short* __restrict__ nbr, const unsigned char* __restrict__ cnt,
    float* __restrict__ out)
{
  const int bi = blockIdx.x;
  const int i = bi % KSEL;
  const int base = bi - i;
  const int f = threadIdx.x;
  float acc = b2[i * FDIM + f] + x1[(size_t)bi * FDIM + f];
  const int c = cnt[bi];
  const unsigned short* nb = nbr + (size_t)bi * 9;
  for (int t = 0; t < c; ++t)
    acc += Hm[(size_t)(base + nb[t]) * FDIM + f];
  out[(size_t)bi * FDIM + f] = tanhf(acc);
}

extern "C" void kernel_launch(void* const* d_in, const int* in_sizes, int n_in,
                              void* d_out, int out_size, void* d_ws, size_t ws_size,
                              hipStream_t stream) {
  const float* feat = (const float*)d_in[0];
  const float* pred = (const float*)d_in[1];
  const float* w1   = (const float*)d_in[2];
  const float* b1   = (const float*)d_in[3];
  const float* w2   = (const float*)d_in[4];
  const float* b2   = (const float*)d_in[5];
  float* out0 = (float*)d_out;                              // (8,2000,128) fp32
  float* out_idx = out0 + (size_t)BATCH * KSEL * FDIM;      // (8,2000) as fp32

  // workspace layout (256B-aligned). NFT (32.768 MB) is dead after gemm1, so
  // x1/Hm overlay it.
  char* ws = (char*)d_ws;
  int*            idx_ws = (int*)(ws + 0);                  //  64000 B
  int*            off_ws = (int*)(ws + 64256);              //  64000 B
  unsigned short* nbr    = (unsigned short*)(ws + 128512);  // 288000 B
  unsigned char*  cnt    = (unsigned char*)(ws + 416512);   //  16000 B
  float*          G      = (float*)(ws + 432640);           // 8.192 MB
  char*           R      = ws + 8624640;                    // 32.768 MB region
  float*          NFT    = (float*)R;                       // gemm1 input
  float*          x1     = (float*)R;                       // after gemm1
  float*          Hm     = (float*)(R + 8388608);           // after gemm1

  topk_kernel<<<BATCH, 1024, 0, stream>>>(pred, idx_ws, off_ws, out_idx);
  nbr_kernel<<<BATCH, 256, 0, stream>>>(idx_ws, nbr, cnt);
  gather_kernel<<<dim3(CIN / 8, BATCH), 256, 0, stream>>>(feat, off_ws, NFT);
  gemm_kernel<CIN, true><<<dim3(63, BATCH), 256, 0, stream>>>(NFT, w1, G);
  x1_kernel<<<BATCH * KSEL, 128, 0, stream>>>(G, b1, nbr, cnt, x1);
  gemm_kernel<FDIM, false><<<dim3(63, BATCH), 256, 0, stream>>>(x1, w2, Hm);
  out_kernel<<<BATCH * KSEL, 128, 0, stream>>>(Hm, x1, b2, nbr, cnt, out0);
}

// Round 4
// 319.021 us; speedup vs baseline: 1.4561x; 1.0540x over previous
//
#include <hip/hip_runtime.h>
#include <cmath>

#define H_DIM 75
#define W_DIM 100
#define HW 7500
#define KSEL 2000
#define BATCH 8
#define CIN 512
#define FDIM 128

__device__ __forceinline__ unsigned int map_key(float f) {
  unsigned int u = __float_as_uint(f);
  return (u & 0x80000000u) ? ~u : (u | 0x80000000u);
}

// K1: per-batch top-K via 4-round radix select (exact Kth-largest key), then
// packed (gt|eq) prefix scan emits selected indices in ascending order with
// lowest-index tie-breaking (matches lax.top_k + sort semantics).
__global__ __launch_bounds__(1024) void topk_kernel(
    const float* __restrict__ pred, int* __restrict__ idx_ws,
    int* __restrict__ off_ws, float* __restrict__ out_idx)
{
  __shared__ unsigned int keys[HW];
  __shared__ unsigned int hist[256];
  __shared__ unsigned int partials[1024];
  __shared__ unsigned int s_prefix, s_kth;
  const int b = blockIdx.x;
  const int tid = threadIdx.x;
  const float* scores = pred + (size_t)b * 3 * HW;  // channel 0 of predict
  for (int i = tid; i < HW; i += 1024) keys[i] = map_key(scores[i]);
  if (tid == 0) { s_prefix = 0u; s_kth = KSEL; }
  __syncthreads();

  // radix select, MSB-first, 8 bits per round
  for (int shift = 24; shift >= 0; shift -= 8) {
    for (int i = tid; i < 256; i += 1024) hist[i] = 0u;
    __syncthreads();
    unsigned int pref = s_prefix;
    unsigned int maskhi = (shift == 24) ? 0u : (0xFFFFFFFFu << (shift + 8));
    for (int i = tid; i < HW; i += 1024) {
      unsigned int k = keys[i];
      if ((k & maskhi) == pref) atomicAdd(&hist[(k >> shift) & 0xFFu], 1u);
    }
    __syncthreads();
    unsigned int kth = s_kth;  // all threads read before any scan barrier
    // suffix sum hist[i] = sum_{j>=i} hist[j]  (Hillis-Steele, reversed)
    for (int off = 1; off < 256; off <<= 1) {
      unsigned int v = 0, add = 0;
      if (tid < 256) { v = hist[tid]; add = (tid + off < 256) ? hist[tid + off] : 0u; }
      __syncthreads();
      if (tid < 256) hist[tid] = v + add;
      __syncthreads();
    }
    if (tid < 256) {
      unsigned int s = hist[tid];
      unsigned int s_above = (tid < 255) ? hist[tid + 1] : 0u;
      if (s >= kth && s_above < kth) {  // exactly one thread matches
        s_prefix = pref | ((unsigned int)tid << shift);
        s_kth = kth - s_above;
      }
    }
    __syncthreads();
  }
  unsigned int thresh = s_prefix;
  __syncthreads();

  // selection scan: gt in low half, eq in high half, packed
  unsigned int local[8];
  unsigned int sum = 0;
  for (int e = 0; e < 8; ++e) {
    int i = tid * 8 + e;
    unsigned int p = 0;
    if (i < HW) {
      unsigned int ky = keys[i];
      if (ky > thresh) p = 1u;
      else if (ky == thresh) p = (1u << 16);
    }
    local[e] = p; sum += p;
  }
  partials[tid] = sum;
  __syncthreads();
  for (int off = 1; off < 1024; off <<= 1) {
    unsigned int v = partials[tid];
    unsigned int add = (tid >= off) ? partials[tid - off] : 0u;
    __syncthreads();
    partials[tid] = v + add;
    __syncthreads();
  }
  unsigned int total = partials[1023];
  unsigned int run = (tid > 0) ? partials[tid - 1] : 0u;
  unsigned int ties = (unsigned int)KSEL - (total & 0xFFFFu);
  for (int e = 0; e < 8; ++e) {
    int i = tid * 8 + e;
    unsigned int p = local[e];
    unsigned int gt_pref = run & 0xFFFFu;
    unsigned int eq_pref = run >> 16;
    bool sel = (p & 1u) || (((p >> 16) != 0u) && eq_pref < ties);
    if (sel) {
      unsigned int pos = gt_pref + (eq_pref < ties ? eq_pref : ties);
      idx_ws[b * KSEL + pos] = i;
      off_ws[b * KSEL + pos] = (i % H_DIM) * W_DIM + i / H_DIM;  // gather offset quirk
      out_idx[b * KSEL + pos] = (float)i;
    }
    run += p;
  }
}

// K2: neighbor lists via inverse grid map. pos_of[cell] -> selected position
// or -1; each node probes its <=9 neighbor cells with independent LDS loads.
// (dy,dx) lexicographic scan == ascending-q order, matching sorted-idx order.
__global__ __launch_bounds__(256) void nbr_kernel(
    const int* __restrict__ idx_ws, unsigned short* __restrict__ nbr,
    unsigned char* __restrict__ cnt)
{
  __shared__ short pos_of[HW];   // 15 KB
  __shared__ int s_idx[KSEL];    //  8 KB
  const int b = blockIdx.x, tid = threadIdx.x;
  for (int i = tid; i < HW; i += 256) pos_of[i] = -1;
  __syncthreads();
  for (int i = tid; i < KSEL; i += 256) {
    int q = idx_ws[b * KSEL + i];
    s_idx[i] = q;
    pos_of[q] = (short)i;
  }
  __syncthreads();
  for (int i = tid; i < KSEL; i += 256) {
    int q = s_idx[i];
    int py = q / W_DIM, px = q % W_DIM;
    int c = 0;
    #pragma unroll
    for (int dy = -1; dy <= 1; ++dy) {
      int y = py + dy;
      if ((unsigned)y >= (unsigned)H_DIM) continue;
      #pragma unroll
      for (int dx = -1; dx <= 1; ++dx) {
        int x = px + dx;
        if ((unsigned)x >= (unsigned)W_DIM) continue;
        short p = pos_of[y * W_DIM + x];
        if (p >= 0) nbr[(size_t)(b * KSEL + i) * 9 + (c++)] = (unsigned short)p;
      }
    }
    cnt[b * KSEL + i] = (unsigned char)c;
  }
}

// K2b: gather+clip+transpose via LDS plane staging. One block per (b, c-plane):
// coalesced float4 read of the 30 KB plane into LDS, scattered gather from LDS
// (fast), coalesced 8 KB write. HBM traffic is pure streaming.
__global__ __launch_bounds__(256) void gather_kernel(
    const float* __restrict__ feat, const int* __restrict__ off_ws,
    float* __restrict__ NFT)
{
  __shared__ __align__(16) float s_plane[HW];  // 30000 B (HW*4 divisible by 16)
  __shared__ int s_off[KSEL];                  //  8000 B
  const int b = blockIdx.y;
  const int c = blockIdx.x;
  const int tid = threadIdx.x;
  const float4* p4 = (const float4*)(feat + ((size_t)b * CIN + c) * HW);
  #pragma unroll 2
  for (int i = tid; i < HW / 4; i += 256)      // 1875 float4
    ((float4*)s_plane)[i] = p4[i];
  for (int i = tid; i < KSEL; i += 256)
    s_off[i] = off_ws[b * KSEL + i];
  __syncthreads();
  float* orow = NFT + ((size_t)b * CIN + c) * KSEL;
  #pragma unroll 4
  for (int n = tid; n < KSEL; n += 256) {
    float v = s_plane[s_off[n]];
    orow[n] = fminf(fmaxf(v, 0.f), 6.f);
  }
}

// K3/K5: OUT[2000x128] = IN[2000xCDIM] @ W[CDIMx128], per batch.
// CMAJOR: IN is NFT [c][n] (clip already applied). else IN is row-major [n][f].
template<int CDIM, bool CMAJOR>
__global__ __launch_bounds__(256) void gemm_kernel(
    const float* __restrict__ in, const float* __restrict__ wmat,
    float* __restrict__ out)
{
  __shared__ __align__(16) float a_lds[32][36];   // [c][n], pad 36
  __shared__ __align__(16) float w_lds[32][128];  // [c][f]
  const int b = blockIdx.y;
  const int n0 = blockIdx.x * 32;
  const int tid = threadIdx.x;
  const int tf = tid & 31, tr = tid >> 5;
  float acc[4][4] = {{0.f}};
  const float* fb = in + (CMAJOR ? (size_t)b * CIN * KSEL : (size_t)b * KSEL * FDIM);
  for (int cc = 0; cc < CDIM; cc += 32) {
    for (int e = tid; e < 32 * 128; e += 256) {
      int c = e >> 7, f = e & 127;
      w_lds[c][f] = wmat[(cc + c) * 128 + f];
    }
    if (CMAJOR) {
      for (int e = tid; e < 1024; e += 256) {
        int c = e >> 5, n = e & 31;
        int row = n0 + n;
        a_lds[c][n] = (row < KSEL) ? fb[(size_t)(cc + c) * KSEL + row] : 0.f;
      }
    } else {
      for (int e = tid; e < 1024; e += 256) {
        int n = e >> 5, c = e & 31;
        int row = n0 + n;
        a_lds[c][n] = (row < KSEL) ? fb[(size_t)row * FDIM + cc + c] : 0.f;
      }
    }
    __syncthreads();
    #pragma unroll
    for (int c = 0; c < 32; ++c) {
      float4 av = *(const float4*)&a_lds[c][tr * 4];
      float4 wv = *(const float4*)&w_lds[c][tf * 4];
      acc[0][0] += av.x * wv.x; acc[0][1] += av.x * wv.y; acc[0][2] += av.x * wv.z; acc[0][3] += av.x * wv.w;
      acc[1][0] += av.y * wv.x; acc[1][1] += av.y * wv.y; acc[1][2] += av.y * wv.z; acc[1][3] += av.y * wv.w;
      acc[2][0] += av.z * wv.x; acc[2][1] += av.z * wv.y; acc[2][2] += av.z * wv.z; acc[2][3] += av.z * wv.w;
      acc[3][0] += av.w * wv.x; acc[3][1] += av.w * wv.y; acc[3][2] += av.w * wv.z; acc[3][3] += av.w * wv.w;
    }
    __syncthreads();
  }
  for (int r = 0; r < 4; ++r) {
    int row = n0 + tr * 4 + r;
    if (row < KSEL) {
      float4 v = make_float4(acc[r][0], acc[r][1], acc[r][2], acc[r][3]);
      *(float4*)&out[((size_t)(b * KSEL + row)) * FDIM + tf * 4] = v;
    }
  }
}

// K4: x1[i] = b1[i] + sum_{j in nbr(i)} G[j]
__global__ __launch_bounds__(128) void x1_kernel(
    const float* __restrict__ G, const float* __restrict__ b1,
    const unsigned short* __restrict__ nbr, const unsigned char* __restrict__ cnt,
    float* __restrict__ x1)
{
  const int bi = blockIdx.x;
  const int i = bi % KSEL;
  const int base = bi - i;
  const int f = threadIdx.x;
  float acc = b1[i * FDIM + f];
  const int c = cnt[bi];
  const unsigned short* nb = nbr + (size_t)bi * 9;
  for (int t = 0; t < c; ++t)
    acc += G[(size_t)(base + nb[t]) * FDIM + f];
  x1[(size_t)bi * FDIM + f] = acc;
}

// K6: out[i] = tanh(b2[i] + x1[i] + sum_{j in nbr(i)} H[j])
__global__ __launch_bounds__(128) void out_kernel(
    const float* __restrict__ Hm, const float* __restrict__ x1,
    const float* __restrict__ b2,
    const unsigned short* __restrict__ nbr, const unsigned char* __restrict__ cnt,
    float* __restrict__ out)
{
  const int bi = blockIdx.x;
  const int i = bi % KSEL;
  const int base = bi - i;
  const int f = threadIdx.x;
  float acc = b2[i * FDIM + f] + x1[(size_t)bi * FDIM + f];
  const int c = cnt[bi];
  const unsigned short* nb = nbr + (size_t)bi * 9;
  for (int t = 0; t < c; ++t)
    acc += Hm[(size_t)(base + nb[t]) * FDIM + f];
  out[(size_t)bi * FDIM + f] = tanhf(acc);
}

extern "C" void kernel_launch(void* const* d_in, const int* in_sizes, int n_in,
                              void* d_out, int out_size, void* d_ws, size_t ws_size,
                              hipStream_t stream) {
  const float* feat = (const float*)d_in[0];
  const float* pred = (const float*)d_in[1];
  const float* w1   = (const float*)d_in[2];
  const float* b1   = (const float*)d_in[3];
  const float* w2   = (const float*)d_in[4];
  const float* b2   = (const float*)d_in[5];
  float* out0 = (float*)d_out;                              // (8,2000,128) fp32
  float* out_idx = out0 + (size_t)BATCH * KSEL * FDIM;      // (8,2000) as fp32

  // workspace layout (256B-aligned). NFT (32.768 MB) is dead after gemm1, so
  // x1/Hm overlay it.
  char* ws = (char*)d_ws;
  int*            idx_ws = (int*)(ws + 0);                  //  64000 B
  int*            off_ws = (int*)(ws + 64256);              //  64000 B
  unsigned short* nbr    = (unsigned short*)(ws + 128512);  // 288000 B
  unsigned char*  cnt    = (unsigned char*)(ws + 416512);   //  16000 B
  float*          G      = (float*)(ws + 432640);           // 8.192 MB
  char*           R      = ws + 8624640;                    // 32.768 MB region
  float*          NFT    = (float*)R;                       // gemm1 input
  float*          x1     = (float*)R;                       // after gemm1
  float*          Hm     = (float*)(R + 8388608);           // after gemm1

  topk_kernel<<<BATCH, 1024, 0, stream>>>(pred, idx_ws, off_ws, out_idx);
  nbr_kernel<<<BATCH, 256, 0, stream>>>(idx_ws, nbr, cnt);
  gather_kernel<<<dim3(CIN, BATCH), 256, 0, stream>>>(feat, off_ws, NFT);
  gemm_kernel<CIN, true><<<dim3(63, BATCH), 256, 0, stream>>>(NFT, w1, G);
  x1_kernel<<<BATCH * KSEL, 128, 0, stream>>>(G, b1, nbr, cnt, x1);
  gemm_kernel<FDIM, false><<<dim3(63, BATCH), 256, 0, stream>>>(x1, w2, Hm);
  out_kernel<<<BATCH * KSEL, 128, 0, stream>>>(Hm, x1, b2, nbr, cnt, out0);
}

// Round 5
// 295.317 us; speedup vs baseline: 1.5730x; 1.0803x over previous
//
#include <hip/hip_runtime.h>
#include <cmath>

#define H_DIM 75
#define W_DIM 100
#define HW 7500
#define KSEL 2000
#define BATCH 8
#define CIN 512
#define FDIM 128

__device__ __forceinline__ unsigned int map_key(float f) {
  unsigned int u = __float_as_uint(f);
  return (u & 0x80000000u) ? ~u : (u | 0x80000000u);
}

// K1 (fused): per-batch top-K via radix select with wave-shuffle scans (few
// barriers), packed (gt|eq) prefix scan emits indices in ascending order with
// lowest-index tie-breaking (matches lax.top_k + sort), then neighbor lists
// via inverse grid map built in the dead `keys` LDS region.
__global__ __launch_bounds__(1024) void topk_nbr_kernel(
    const float* __restrict__ pred, int* __restrict__ off_ws,
    float* __restrict__ out_idx, unsigned short* __restrict__ nbr,
    unsigned char* __restrict__ cnt)
{
  __shared__ unsigned int keys[HW];      // 30 KB; reused: pos_of[HW] (short) + s_idx[KSEL] (int)
  __shared__ unsigned int hist[256];
  __shared__ unsigned int partials[16];
  __shared__ unsigned int s_prefix, s_kth;
  const int b = blockIdx.x;
  const int tid = threadIdx.x;
  const int lane = tid & 63, w = tid >> 6;
  const float* scores = pred + (size_t)b * 3 * HW;  // channel 0 of predict
  for (int i = tid; i < HW; i += 1024) keys[i] = map_key(scores[i]);
  if (tid == 0) { s_prefix = 0u; s_kth = KSEL; }
  __syncthreads();

  // radix select, MSB-first, 8 bits/round; suffix scan by wave 0 via shfl
  for (int shift = 24; shift >= 0; shift -= 8) {
    if (tid < 256) hist[tid] = 0u;
    __syncthreads();
    unsigned int pref = s_prefix;
    unsigned int maskhi = (shift == 24) ? 0u : (0xFFFFFFFFu << (shift + 8));
    for (int i = tid; i < HW; i += 1024) {
      unsigned int k = keys[i];
      if ((k & maskhi) == pref) atomicAdd(&hist[(k >> shift) & 0xFFu], 1u);
    }
    __syncthreads();
    if (tid < 64) {
      unsigned int b0 = hist[tid * 4], b1 = hist[tid * 4 + 1];
      unsigned int b2 = hist[tid * 4 + 2], b3 = hist[tid * 4 + 3];
      unsigned int kth = s_kth;
      unsigned int T = b0 + b1 + b2 + b3;
      #pragma unroll
      for (int off = 1; off < 64; off <<= 1) {
        unsigned int t = __shfl_down(T, off, 64);
        if (tid + off < 64) T += t;       // inclusive suffix of lane totals
      }
      unsigned int U = __shfl_down(T, 1, 64);
      if (tid == 63) U = 0u;              // suffix strictly after this lane
      unsigned int s3 = b3 + U, s2 = b2 + s3, s1 = b1 + s2, s0 = b0 + s1;
      if (s0 >= kth && s1 < kth) { s_prefix = pref | ((unsigned)(4 * tid + 0) << shift); s_kth = kth - s1; }
      if (s1 >= kth && s2 < kth) { s_prefix = pref | ((unsigned)(4 * tid + 1) << shift); s_kth = kth - s2; }
      if (s2 >= kth && s3 < kth) { s_prefix = pref | ((unsigned)(4 * tid + 2) << shift); s_kth = kth - s3; }
      if (s3 >= kth && U  < kth) { s_prefix = pref | ((unsigned)(4 * tid + 3) << shift); s_kth = kth - U; }
    }
    __syncthreads();
  }
  const unsigned int thresh = s_prefix;

  // selection flags: gt in low 16 bits, eq in high 16, packed
  unsigned int local[8];
  unsigned int sum = 0;
  #pragma unroll
  for (int e = 0; e < 8; ++e) {
    int i = tid * 8 + e;
    unsigned int p = 0;
    if (i < HW) {
      unsigned int ky = keys[i];
      if (ky > thresh) p = 1u;
      else if (ky == thresh) p = (1u << 16);
    }
    local[e] = p; sum += p;
  }
  __syncthreads();   // keys dead beyond this point — safe to overlay
  short* pos_of  = (short*)keys;                 // 15000 B
  int*   s_idx_sh = (int*)((char*)keys + 15000); //  8000 B
  for (int i = tid; i < HW; i += 1024) pos_of[i] = -1;

  // two-level exclusive prefix scan: shfl within wave, 16-entry cross-wave
  unsigned int inc = sum;
  #pragma unroll
  for (int off = 1; off < 64; off <<= 1) {
    unsigned int t = __shfl_up(inc, off, 64);
    if (lane >= off) inc += t;
  }
  if (lane == 63) partials[w] = inc;
  __syncthreads();
  if (tid < 16) {
    unsigned int v = partials[tid];
    #pragma unroll
    for (int off = 1; off < 16; off <<= 1) {
      unsigned int t = __shfl_up(v, off, 64);
      if (tid >= off) v += t;
    }
    partials[tid] = v;
  }
  __syncthreads();
  unsigned int total = partials[15];
  unsigned int run = (w ? partials[w - 1] : 0u) + inc - sum;
  unsigned int ties = (unsigned int)KSEL - (total & 0xFFFFu);
  #pragma unroll
  for (int e = 0; e < 8; ++e) {
    int i = tid * 8 + e;
    unsigned int p = local[e];
    unsigned int gt_pref = run & 0xFFFFu;
    unsigned int eq_pref = run >> 16;
    bool sel = (p & 1u) || (((p >> 16) != 0u) && eq_pref < ties);
    if (sel) {
      unsigned int pos = gt_pref + (eq_pref < ties ? eq_pref : ties);
      off_ws[b * KSEL + pos] = (i % H_DIM) * W_DIM + i / H_DIM;  // gather offset quirk
      out_idx[b * KSEL + pos] = (float)i;
      s_idx_sh[pos] = i;
      pos_of[i] = (short)pos;
    }
    run += p;
  }
  __syncthreads();

  // neighbor lists: probe <=9 cells; (dy,dx) lex order == ascending position
  for (int i = tid; i < KSEL; i += 1024) {
    int q = s_idx_sh[i];
    int py = q / W_DIM, px = q % W_DIM;
    int c = 0;
    #pragma unroll
    for (int dy = -1; dy <= 1; ++dy) {
      int y = py + dy;
      if ((unsigned)y >= (unsigned)H_DIM) continue;
      #pragma unroll
      for (int dx = -1; dx <= 1; ++dx) {
        int x = px + dx;
        if ((unsigned)x >= (unsigned)W_DIM) continue;
        short p = pos_of[y * W_DIM + x];
        if (p >= 0) nbr[(size_t)(b * KSEL + i) * 9 + (c++)] = (unsigned short)p;
      }
    }
    cnt[b * KSEL + i] = (unsigned char)c;
  }
}

// K2b: gather+clip+transpose via LDS plane staging. One block per (b, c-plane).
__global__ __launch_bounds__(256) void gather_kernel(
    const float* __restrict__ feat, const int* __restrict__ off_ws,
    float* __restrict__ NFT)
{
  __shared__ __align__(16) float s_plane[HW];
  __shared__ int s_off[KSEL];
  const int b = blockIdx.y;
  const int c = blockIdx.x;
  const int tid = threadIdx.x;
  const float4* p4 = (const float4*)(feat + ((size_t)b * CIN + c) * HW);
  #pragma unroll 2
  for (int i = tid; i < HW / 4; i += 256)
    ((float4*)s_plane)[i] = p4[i];
  for (int i = tid; i < KSEL; i += 256)
    s_off[i] = off_ws[b * KSEL + i];
  __syncthreads();
  float4* orow4 = (float4*)(NFT + ((size_t)b * CIN + c) * KSEL);
  for (int n4 = tid; n4 < KSEL / 4; n4 += 256) {
    int n = n4 * 4;
    float4 v;
    v.x = fminf(fmaxf(s_plane[s_off[n    ]], 0.f), 6.f);
    v.y = fminf(fmaxf(s_plane[s_off[n + 1]], 0.f), 6.f);
    v.z = fminf(fmaxf(s_plane[s_off[n + 2]], 0.f), 6.f);
    v.w = fminf(fmaxf(s_plane[s_off[n + 3]], 0.f), 6.f);
    orow4[n4] = v;
  }
}

// K3/K5: OUT[2000x128] = IN[2000xCDIM] @ W[CDIMx128], per batch.
// CMAJOR: IN is NFT [c][n]. else IN is row-major [n][f] (transpose-staged).
// All staging is float4. OOB tile rows (n>=2000, last block) read in-bounds
// garbage from the workspace and are never stored.
template<int CDIM, bool CMAJOR>
__global__ __launch_bounds__(256) void gemm_kernel(
    const float* __restrict__ in, const float* __restrict__ wmat,
    float* __restrict__ out)
{
  __shared__ __align__(16) float a_lds[32][36];   // row stride 144 B (16B-mult)
  __shared__ __align__(16) float w_lds[32][128];
  const int b = blockIdx.y;
  const int n0 = blockIdx.x * 32;
  const int tid = threadIdx.x;
  const int tf = tid & 31, tr = tid >> 5;
  float acc[4][4] = {{0.f}};
  const float* fb = in + (CMAJOR ? (size_t)b * CIN * KSEL : (size_t)b * KSEL * FDIM);
  for (int cc = 0; cc < CDIM; cc += 32) {
    const float4* w4 = (const float4*)(wmat + cc * 128);
    #pragma unroll
    for (int e = tid; e < 1024; e += 256) {       // 4 float4 per thread
      int c = e >> 5, f4 = e & 31;
      ((float4*)&w_lds[c][0])[f4] = w4[e];
    }
    if (CMAJOR) {
      int c = tid >> 3, n4 = tid & 7;             // 1 float4 per thread
      ((float4*)&a_lds[c][0])[n4] =
          *(const float4*)&fb[(size_t)(cc + c) * KSEL + n0 + n4 * 4];
    } else {
      int n = tid >> 3, c4 = tid & 7;             // float4 load + LDS transpose
      float4 v = *(const float4*)&fb[(size_t)(n0 + n) * FDIM + cc + c4 * 4];
      a_lds[c4 * 4 + 0][n] = v.x;
      a_lds[c4 * 4 + 1][n] = v.y;
      a_lds[c4 * 4 + 2][n] = v.z;
      a_lds[c4 * 4 + 3][n] = v.w;
    }
    __syncthreads();
    #pragma unroll
    for (int c = 0; c < 32; ++c) {
      float4 av = *(const float4*)&a_lds[c][tr * 4];
      float4 wv = *(const float4*)&w_lds[c][tf * 4];
      acc[0][0] += av.x * wv.x; acc[0][1] += av.x * wv.y; acc[0][2] += av.x * wv.z; acc[0][3] += av.x * wv.w;
      acc[1][0] += av.y * wv.x; acc[1][1] += av.y * wv.y; acc[1][2] += av.y * wv.z; acc[1][3] += av.y * wv.w;
      acc[2][0] += av.z * wv.x; acc[2][1] += av.z * wv.y; acc[2][2] += av.z * wv.z; acc[2][3] += av.z * wv.w;
      acc[3][0] += av.w * wv.x; acc[3][1] += av.w * wv.y; acc[3][2] += av.w * wv.z; acc[3][3] += av.w * wv.w;
    }
    __syncthreads();
  }
  #pragma unroll
  for (int r = 0; r < 4; ++r) {
    int row = n0 + tr * 4 + r;
    if (row < KSEL) {
      float4 v = make_float4(acc[r][0], acc[r][1], acc[r][2], acc[r][3]);
      *(float4*)&out[((size_t)(b * KSEL + row)) * FDIM + tf * 4] = v;
    }
  }
}

// K4: x1[i] = b1[i] + sum_{j in nbr(i)} G[j].  8 nodes/block, 32 lanes/node,
// float4 rows.
__global__ __launch_bounds__(256) void x1_kernel(
    const float* __restrict__ G, const float* __restrict__ b1,
    const unsigned short* __restrict__ nbr, const unsigned char* __restrict__ cnt,
    float* __restrict__ x1)
{
  const int g = threadIdx.x >> 5, lane = threadIdx.x & 31;
  const int node = blockIdx.x * 8 + g;
  const int bb = blockIdx.y;
  const size_t bi = (size_t)bb * KSEL + node;
  float4 acc = ((const float4*)b1)[node * 32 + lane];
  const int c = cnt[bi];
  const unsigned short* nb = nbr + bi * 9;
  const float4* G4 = (const float4*)G + (size_t)bb * KSEL * 32;
  for (int t = 0; t < c; ++t) {
    float4 v = G4[(size_t)nb[t] * 32 + lane];
    acc.x += v.x; acc.y += v.y; acc.z += v.z; acc.w += v.w;
  }
  ((float4*)x1)[bi * 32 + lane] = acc;
}

// K6: out[i] = tanh(b2[i] + x1[i] + sum_{j in nbr(i)} H[j])
__global__ __launch_bounds__(256) void out_kernel(
    const float* __restrict__ Hm, const float* __restrict__ x1,
    const float* __restrict__ b2,
    const unsigned short* __restrict__ nbr, const unsigned char* __restrict__ cnt,
    float* __restrict__ out)
{
  const int g = threadIdx.x >> 5, lane = threadIdx.x & 31;
  const int node = blockIdx.x * 8 + g;
  const int bb = blockIdx.y;
  const size_t bi = (size_t)bb * KSEL + node;
  float4 acc = ((const float4*)b2)[node * 32 + lane];
  float4 xv = ((const float4*)x1)[bi * 32 + lane];
  acc.x += xv.x; acc.y += xv.y; acc.z += xv.z; acc.w += xv.w;
  const int c = cnt[bi];
  const unsigned short* nb = nbr + bi * 9;
  const float4* H4 = (const float4*)Hm + (size_t)bb * KSEL * 32;
  for (int t = 0; t < c; ++t) {
    float4 v = H4[(size_t)nb[t] * 32 + lane];
    acc.x += v.x; acc.y += v.y; acc.z += v.z; acc.w += v.w;
  }
  float4 r;
  r.x = tanhf(acc.x); r.y = tanhf(acc.y); r.z = tanhf(acc.z); r.w = tanhf(acc.w);
  ((float4*)out)[bi * 32 + lane] = r;
}

extern "C" void kernel_launch(void* const* d_in, const int* in_sizes, int n_in,
                              void* d_out, int out_size, void* d_ws, size_t ws_size,
                              hipStream_t stream) {
  const float* feat = (const float*)d_in[0];
  const float* pred = (const float*)d_in[1];
  const float* w1   = (const float*)d_in[2];
  const float* b1   = (const float*)d_in[3];
  const float* w2   = (const float*)d_in[4];
  const float* b2   = (const float*)d_in[5];
  float* out0 = (float*)d_out;                              // (8,2000,128) fp32
  float* out_idx = out0 + (size_t)BATCH * KSEL * FDIM;      // (8,2000) as fp32

  // workspace layout (256B-aligned). NFT (32.768 MB) is dead after gemm1, so
  // x1/Hm overlay it.
  char* ws = (char*)d_ws;
  int*            off_ws = (int*)(ws + 0);                  //  64000 B
  unsigned short* nbr    = (unsigned short*)(ws + 64256);   // 288000 B
  unsigned char*  cnt    = (unsigned char*)(ws + 352512);   //  16000 B
  float*          G      = (float*)(ws + 368640);           // 8.192 MB
  char*           R      = ws + 8560640;                    // 32.768 MB region
  float*          NFT    = (float*)R;                       // gemm1 input
  float*          x1     = (float*)R;                       // after gemm1
  float*          Hm     = (float*)(R + 8388608);           // after gemm1

  topk_nbr_kernel<<<BATCH, 1024, 0, stream>>>(pred, off_ws, out_idx, nbr, cnt);
  gather_kernel<<<dim3(CIN, BATCH), 256, 0, stream>>>(feat, off_ws, NFT);
  gemm_kernel<CIN, true><<<dim3(63, BATCH), 256, 0, stream>>>(NFT, w1, G);
  x1_kernel<<<dim3(KSEL / 8, BATCH), 256, 0, stream>>>(G, b1, nbr, cnt, x1);
  gemm_kernel<FDIM, false><<<dim3(63, BATCH), 256, 0, stream>>>(x1, w2, Hm);
  out_kernel<<<dim3(KSEL / 8, BATCH), 256, 0, stream>>>(Hm, x1, b2, nbr, cnt, out0);
}

// Round 6
// 288.544 us; speedup vs baseline: 1.6099x; 1.0235x over previous
//
#include <hip/hip_runtime.h>
#include <cmath>

#define H_DIM 75
#define W_DIM 100
#define HW 7500
#define KSEL 2000
#define BATCH 8
#define CIN 512
#define FDIM 128

__device__ __forceinline__ unsigned int map_key(float f) {
  unsigned int u = __float_as_uint(f);
  return (u & 0x80000000u) ? ~u : (u | 0x80000000u);
}

__device__ __forceinline__ float fast_tanh(float x) {
  // 1 - 2/(e^{2x}+1); exp->inf gives 1, exp->0 gives -1. ~1e-6 abs err.
  float e = __expf(2.0f * x);
  return 1.0f - 2.0f * __builtin_amdgcn_rcpf(e + 1.0f);
}

// K1 (fused): per-batch top-K via radix select with wave-shuffle scans, packed
// (gt|eq) prefix scan emits indices in ascending order with lowest-index
// tie-breaking (matches lax.top_k + sort), then neighbor lists via inverse
// grid map built in the dead `keys` LDS region. nbr rows padded to 9 (pad=0)
// so consumers may load all 9 unconditionally.
__global__ __launch_bounds__(1024) void topk_nbr_kernel(
    const float* __restrict__ pred, int* __restrict__ off_ws,
    float* __restrict__ out_idx, unsigned short* __restrict__ nbr,
    unsigned char* __restrict__ cnt)
{
  __shared__ unsigned int keys[HW];      // 30 KB; reused: pos_of[HW] (short) + s_idx[KSEL] (int)
  __shared__ unsigned int hist[256];
  __shared__ unsigned int partials[16];
  __shared__ unsigned int s_prefix, s_kth;
  const int b = blockIdx.x;
  const int tid = threadIdx.x;
  const int lane = tid & 63, w = tid >> 6;
  const float* scores = pred + (size_t)b * 3 * HW;  // channel 0 of predict
  for (int i = tid; i < HW; i += 1024) keys[i] = map_key(scores[i]);
  if (tid == 0) { s_prefix = 0u; s_kth = KSEL; }
  __syncthreads();

  // radix select, MSB-first, 8 bits/round; suffix scan by wave 0 via shfl
  for (int shift = 24; shift >= 0; shift -= 8) {
    if (tid < 256) hist[tid] = 0u;
    __syncthreads();
    unsigned int pref = s_prefix;
    unsigned int maskhi = (shift == 24) ? 0u : (0xFFFFFFFFu << (shift + 8));
    for (int i = tid; i < HW; i += 1024) {
      unsigned int k = keys[i];
      if ((k & maskhi) == pref) atomicAdd(&hist[(k >> shift) & 0xFFu], 1u);
    }
    __syncthreads();
    if (tid < 64) {
      unsigned int b0 = hist[tid * 4], b1 = hist[tid * 4 + 1];
      unsigned int b2 = hist[tid * 4 + 2], b3 = hist[tid * 4 + 3];
      unsigned int kth = s_kth;
      unsigned int T = b0 + b1 + b2 + b3;
      #pragma unroll
      for (int off = 1; off < 64; off <<= 1) {
        unsigned int t = __shfl_down(T, off, 64);
        if (tid + off < 64) T += t;       // inclusive suffix of lane totals
      }
      unsigned int U = __shfl_down(T, 1, 64);
      if (tid == 63) U = 0u;              // suffix strictly after this lane
      unsigned int s3 = b3 + U, s2 = b2 + s3, s1 = b1 + s2, s0 = b0 + s1;
      if (s0 >= kth && s1 < kth) { s_prefix = pref | ((unsigned)(4 * tid + 0) << shift); s_kth = kth - s1; }
      if (s1 >= kth && s2 < kth) { s_prefix = pref | ((unsigned)(4 * tid + 1) << shift); s_kth = kth - s2; }
      if (s2 >= kth && s3 < kth) { s_prefix = pref | ((unsigned)(4 * tid + 2) << shift); s_kth = kth - s3; }
      if (s3 >= kth && U  < kth) { s_prefix = pref | ((unsigned)(4 * tid + 3) << shift); s_kth = kth - U; }
    }
    __syncthreads();
  }
  const unsigned int thresh = s_prefix;

  // selection flags: gt in low 16 bits, eq in high 16, packed
  unsigned int local[8];
  unsigned int sum = 0;
  #pragma unroll
  for (int e = 0; e < 8; ++e) {
    int i = tid * 8 + e;
    unsigned int p = 0;
    if (i < HW) {
      unsigned int ky = keys[i];
      if (ky > thresh) p = 1u;
      else if (ky == thresh) p = (1u << 16);
    }
    local[e] = p; sum += p;
  }
  __syncthreads();   // keys dead beyond this point — safe to overlay
  short* pos_of  = (short*)keys;                 // 15000 B
  int*   s_idx_sh = (int*)((char*)keys + 15000); //  8000 B
  for (int i = tid; i < HW; i += 1024) pos_of[i] = -1;

  // two-level exclusive prefix scan: shfl within wave, 16-entry cross-wave
  unsigned int inc = sum;
  #pragma unroll
  for (int off = 1; off < 64; off <<= 1) {
    unsigned int t = __shfl_up(inc, off, 64);
    if (lane >= off) inc += t;
  }
  if (lane == 63) partials[w] = inc;
  __syncthreads();
  if (tid < 16) {
    unsigned int v = partials[tid];
    #pragma unroll
    for (int off = 1; off < 16; off <<= 1) {
      unsigned int t = __shfl_up(v, off, 64);
      if (tid >= off) v += t;
    }
    partials[tid] = v;
  }
  __syncthreads();
  unsigned int total = partials[15];
  unsigned int run = (w ? partials[w - 1] : 0u) + inc - sum;
  unsigned int ties = (unsigned int)KSEL - (total & 0xFFFFu);
  #pragma unroll
  for (int e = 0; e < 8; ++e) {
    int i = tid * 8 + e;
    unsigned int p = local[e];
    unsigned int gt_pref = run & 0xFFFFu;
    unsigned int eq_pref = run >> 16;
    bool sel = (p & 1u) || (((p >> 16) != 0u) && eq_pref < ties);
    if (sel) {
      unsigned int pos = gt_pref + (eq_pref < ties ? eq_pref : ties);
      off_ws[b * KSEL + pos] = (i % H_DIM) * W_DIM + i / H_DIM;  // gather offset quirk
      out_idx[b * KSEL + pos] = (float)i;
      s_idx_sh[pos] = i;
      pos_of[i] = (short)pos;
    }
    run += p;
  }
  __syncthreads();

  // neighbor lists: probe <=9 cells; (dy,dx) lex order == ascending position.
  // Always write 9 slots (pad = 0, a valid row; consumers mask by cnt).
  for (int i = tid; i < KSEL; i += 1024) {
    int q = s_idx_sh[i];
    int py = q / W_DIM, px = q % W_DIM;
    unsigned short tmp[9];
    int c = 0;
    #pragma unroll
    for (int dy = -1; dy <= 1; ++dy) {
      int y = py + dy;
      if ((unsigned)y >= (unsigned)H_DIM) continue;
      #pragma unroll
      for (int dx = -1; dx <= 1; ++dx) {
        int x = px + dx;
        if ((unsigned)x >= (unsigned)W_DIM) continue;
        short p = pos_of[y * W_DIM + x];
        if (p >= 0) tmp[c++] = (unsigned short)p;
      }
    }
    #pragma unroll
    for (int t = 0; t < 9; ++t)
      nbr[(size_t)(b * KSEL + i) * 9 + t] = (t < c) ? tmp[t] : (unsigned short)0;
    cnt[b * KSEL + i] = (unsigned char)c;
  }
}

// K2b: gather+clip+transpose via LDS plane staging. One block per (b, c-plane),
// 512 threads (8 waves; 30 KB LDS -> 4 resident blocks = 32 waves/CU).
// Offsets read directly as coalesced uint4 (L2-resident), no LDS staging.
__global__ __launch_bounds__(512) void gather_kernel(
    const float* __restrict__ feat, const int* __restrict__ off_ws,
    float* __restrict__ NFT)
{
  __shared__ __align__(16) float s_plane[HW];
  const int b = blockIdx.y;
  const int c = blockIdx.x;
  const int tid = threadIdx.x;
  const float4* p4 = (const float4*)(feat + ((size_t)b * CIN + c) * HW);
  float4* sp4 = (float4*)s_plane;
  #pragma unroll
  for (int i = tid; i < HW / 4; i += 512)   // 1875 float4, ~3.7 iters
    sp4[i] = p4[i];
  __syncthreads();
  if (tid < KSEL / 4) {
    const uint4* o4 = (const uint4*)off_ws + (size_t)b * (KSEL / 4);
    uint4 o = o4[tid];
    float4 v;
    v.x = fminf(fmaxf(s_plane[o.x], 0.f), 6.f);
    v.y = fminf(fmaxf(s_plane[o.y], 0.f), 6.f);
    v.z = fminf(fmaxf(s_plane[o.z], 0.f), 6.f);
    v.w = fminf(fmaxf(s_plane[o.w], 0.f), 6.f);
    float4* orow4 = (float4*)(NFT + ((size_t)b * CIN + c) * KSEL);
    orow4[tid] = v;
  }
}

// K3/K5: OUT[2000x128] = IN[2000xCDIM] @ W[CDIMx128], per batch.
// CMAJOR: IN is NFT [c][n]. else IN is row-major [n][f] (transpose-staged).
template<int CDIM, bool CMAJOR>
__global__ __launch_bounds__(256) void gemm_kernel(
    const float* __restrict__ in, const float* __restrict__ wmat,
    float* __restrict__ out)
{
  __shared__ __align__(16) float a_lds[32][36];   // row stride 144 B (16B-mult)
  __shared__ __align__(16) float w_lds[32][128];
  const int b = blockIdx.y;
  const int n0 = blockIdx.x * 32;
  const int tid = threadIdx.x;
  const int tf = tid & 31, tr = tid >> 5;
  float acc[4][4] = {{0.f}};
  const float* fb = in + (CMAJOR ? (size_t)b * CIN * KSEL : (size_t)b * KSEL * FDIM);
  for (int cc = 0; cc < CDIM; cc += 32) {
    const float4* w4 = (const float4*)(wmat + cc * 128);
    #pragma unroll
    for (int e = tid; e < 1024; e += 256) {       // 4 float4 per thread
      int c = e >> 5, f4 = e & 31;
      ((float4*)&w_lds[c][0])[f4] = w4[e];
    }
    if (CMAJOR) {
      int c = tid >> 3, n4 = tid & 7;             // 1 float4 per thread
      ((float4*)&a_lds[c][0])[n4] =
          *(const float4*)&fb[(size_t)(cc + c) * KSEL + n0 + n4 * 4];
    } else {
      int n = tid >> 3, c4 = tid & 7;             // float4 load + LDS transpose
      float4 v = *(const float4*)&fb[(size_t)(n0 + n) * FDIM + cc + c4 * 4];
      a_lds[c4 * 4 + 0][n] = v.x;
      a_lds[c4 * 4 + 1][n] = v.y;
      a_lds[c4 * 4 + 2][n] = v.z;
      a_lds[c4 * 4 + 3][n] = v.w;
    }
    __syncthreads();
    #pragma unroll
    for (int c = 0; c < 32; ++c) {
      float4 av = *(const float4*)&a_lds[c][tr * 4];
      float4 wv = *(const float4*)&w_lds[c][tf * 4];
      acc[0][0] += av.x * wv.x; acc[0][1] += av.x * wv.y; acc[0][2] += av.x * wv.z; acc[0][3] += av.x * wv.w;
      acc[1][0] += av.y * wv.x; acc[1][1] += av.y * wv.y; acc[1][2] += av.y * wv.z; acc[1][3] += av.y * wv.w;
      acc[2][0] += av.z * wv.x; acc[2][1] += av.z * wv.y; acc[2][2] += av.z * wv.z; acc[2][3] += av.z * wv.w;
      acc[3][0] += av.w * wv.x; acc[3][1] += av.w * wv.y; acc[3][2] += av.w * wv.z; acc[3][3] += av.w * wv.w;
    }
    __syncthreads();
  }
  #pragma unroll
  for (int r = 0; r < 4; ++r) {
    int row = n0 + tr * 4 + r;
    if (row < KSEL) {
      float4 v = make_float4(acc[r][0], acc[r][1], acc[r][2], acc[r][3]);
      *(float4*)&out[((size_t)(b * KSEL + row)) * FDIM + tf * 4] = v;
    }
  }
}

// K4: x1[i] = b1[i] + sum_{j in nbr(i)} G[j]. 8 nodes/block, 32 lanes/node,
// float4 rows; all 9 neighbor loads issued unconditionally (padded nbr),
// accumulation masked -> MLP 9 instead of serial dependent loop.
__global__ __launch_bounds__(256) void x1_kernel(
    const float* __restrict__ G, const float* __restrict__ b1,
    const unsigned short* __restrict__ nbr, const unsigned char* __restrict__ cnt,
    float* __restrict__ x1)
{
  const int g = threadIdx.x >> 5, lane = threadIdx.x & 31;
  const int node = blockIdx.x * 8 + g;
  const int bb = blockIdx.y;
  const size_t bi = (size_t)bb * KSEL + node;
  const unsigned short* nb = nbr + bi * 9;
  unsigned short idx[9];
  #pragma unroll
  for (int t = 0; t < 9; ++t) idx[t] = nb[t];
  const int c = cnt[bi];
  const float4* G4 = (const float4*)G + (size_t)bb * KSEL * 32;
  float4 v[9];
  #pragma unroll
  for (int t = 0; t < 9; ++t) v[t] = G4[(size_t)idx[t] * 32 + lane];
  float4 acc = ((const float4*)b1)[node * 32 + lane];
  #pragma unroll
  for (int t = 0; t < 9; ++t) {
    float m = (t < c) ? 1.f : 0.f;
    acc.x = fmaf(v[t].x, m, acc.x);
    acc.y = fmaf(v[t].y, m, acc.y);
    acc.z = fmaf(v[t].z, m, acc.z);
    acc.w = fmaf(v[t].w, m, acc.w);
  }
  ((float4*)x1)[bi * 32 + lane] = acc;
}

// K6: out[i] = tanh(b2[i] + x1[i] + sum_{j in nbr(i)} H[j])
__global__ __launch_bounds__(256) void out_kernel(
    const float* __restrict__ Hm, const float* __restrict__ x1,
    const float* __restrict__ b2,
    const unsigned short* __restrict__ nbr, const unsigned char* __restrict__ cnt,
    float* __restrict__ out)
{
  const int g = threadIdx.x >> 5, lane = threadIdx.x & 31;
  const int node = blockIdx.x * 8 + g;
  const int bb = blockIdx.y;
  const size_t bi = (size_t)bb * KSEL + node;
  const unsigned short* nb = nbr + bi * 9;
  unsigned short idx[9];
  #pragma unroll
  for (int t = 0; t < 9; ++t) idx[t] = nb[t];
  const int c = cnt[bi];
  const float4* H4 = (const float4*)Hm + (size_t)bb * KSEL * 32;
  float4 v[9];
  #pragma unroll
  for (int t = 0; t < 9; ++t) v[t] = H4[(size_t)idx[t] * 32 + lane];
  float4 acc = ((const float4*)b2)[node * 32 + lane];
  float4 xv = ((const float4*)x1)[bi * 32 + lane];
  acc.x += xv.x; acc.y += xv.y; acc.z += xv.z; acc.w += xv.w;
  #pragma unroll
  for (int t = 0; t < 9; ++t) {
    float m = (t < c) ? 1.f : 0.f;
    acc.x = fmaf(v[t].x, m, acc.x);
    acc.y = fmaf(v[t].y, m, acc.y);
    acc.z = fmaf(v[t].z, m, acc.z);
    acc.w = fmaf(v[t].w, m, acc.w);
  }
  float4 r;
  r.x = fast_tanh(acc.x); r.y = fast_tanh(acc.y);
  r.z = fast_tanh(acc.z); r.w = fast_tanh(acc.w);
  ((float4*)out)[bi * 32 + lane] = r;
}

extern "C" void kernel_launch(void* const* d_in, const int* in_sizes, int n_in,
                              void* d_out, int out_size, void* d_ws, size_t ws_size,
                              hipStream_t stream) {
  const float* feat = (const float*)d_in[0];
  const float* pred = (const float*)d_in[1];
  const float* w1   = (const float*)d_in[2];
  const float* b1   = (const float*)d_in[3];
  const float* w2   = (const float*)d_in[4];
  const float* b2   = (const float*)d_in[5];
  float* out0 = (float*)d_out;                              // (8,2000,128) fp32
  float* out_idx = out0 + (size_t)BATCH * KSEL * FDIM;      // (8,2000) as fp32

  // workspace layout (256B-aligned). NFT (32.768 MB) is dead after gemm1, so
  // x1/Hm overlay it.
  char* ws = (char*)d_ws;
  int*            off_ws = (int*)(ws + 0);                  //  64000 B
  unsigned short* nbr    = (unsigned short*)(ws + 64256);   // 288000 B
  unsigned char*  cnt    = (unsigned char*)(ws + 352512);   //  16000 B
  float*          G      = (float*)(ws + 368640);           // 8.192 MB
  char*           R      = ws + 8560640;                    // 32.768 MB region
  float*          NFT    = (float*)R;                       // gemm1 input
  float*          x1     = (float*)R;                       // after gemm1
  float*          Hm     = (float*)(R + 8388608);           // after gemm1

  topk_nbr_kernel<<<BATCH, 1024, 0, stream>>>(pred, off_ws, out_idx, nbr, cnt);
  gather_kernel<<<dim3(CIN, BATCH), 512, 0, stream>>>(feat, off_ws, NFT);
  gemm_kernel<CIN, true><<<dim3(63, BATCH), 256, 0, stream>>>(NFT, w1, G);
  x1_kernel<<<dim3(KSEL / 8, BATCH), 256, 0, stream>>>(G, b1, nbr, cnt, x1);
  gemm_kernel<FDIM, false><<<dim3(63, BATCH), 256, 0, stream>>>(x1, w2, Hm);
  out_kernel<<<dim3(KSEL / 8, BATCH), 256, 0, stream>>>(Hm, x1, b2, nbr, cnt, out0);
}

// Round 7
// 268.043 us; speedup vs baseline: 1.7330x; 1.0765x over previous
//
#include <hip/hip_runtime.h>
#include <cmath>

#define H_DIM 75
#define W_DIM 100
#define HW 7500
#define KSEL 2000
#define BATCH 8
#define CIN 512
#define FDIM 128

typedef short v4s __attribute__((ext_vector_type(4)));
typedef short v8s __attribute__((ext_vector_type(8)));
typedef float v16f __attribute__((ext_vector_type(16)));

__device__ __forceinline__ unsigned int map_key(float f) {
  unsigned int u = __float_as_uint(f);
  return (u & 0x80000000u) ? ~u : (u | 0x80000000u);
}

__device__ __forceinline__ float fast_tanh(float x) {
  float e = __expf(2.0f * x);
  return 1.0f - 2.0f * __builtin_amdgcn_rcpf(e + 1.0f);
}

__device__ __forceinline__ unsigned short bf16_rne(float v) {
  unsigned int u = __float_as_uint(v);
  unsigned int r = u + 0x7FFFu + ((u >> 16) & 1u);
  return (unsigned short)(r >> 16);
}
__device__ __forceinline__ float bf16_to_f(unsigned short h) {
  return __uint_as_float(((unsigned int)h) << 16);
}

// K1 (fused): blocks 0..7 do per-batch top-K (radix select + packed scan,
// exact lax.top_k+sort semantics) then neighbor lists. Blocks 8..15 split
// w1 into transposed bf16 hi/lo planes for the MFMA GEMM.
__global__ __launch_bounds__(1024) void topk_nbr_kernel(
    const float* __restrict__ pred, const float* __restrict__ w1,
    int* __restrict__ off_ws, float* __restrict__ out_idx,
    unsigned short* __restrict__ nbr, unsigned char* __restrict__ cnt,
    unsigned short* __restrict__ w1t_hi, unsigned short* __restrict__ w1t_lo)
{
  __shared__ unsigned int keys[HW];      // 30 KB; reused: pos_of + s_idx
  __shared__ unsigned int hist[256];
  __shared__ unsigned int partials[16];
  __shared__ unsigned int s_prefix, s_kth;
  const int tid = threadIdx.x;

  if (blockIdx.x >= BATCH) {             // w1 split: 8 blocks x 1024 thr
    int base = (blockIdx.x - BATCH) * 1024 + tid;
    #pragma unroll
    for (int e = base; e < CIN * FDIM; e += 8 * 1024) {
      int k = e & (CIN - 1), f = e >> 9;       // k-inner: coalesced writes
      float v = w1[k * FDIM + f];
      unsigned short hi = bf16_rne(v);
      unsigned short lo = bf16_rne(v - bf16_to_f(hi));
      w1t_hi[(size_t)f * CIN + k] = hi;
      w1t_lo[(size_t)f * CIN + k] = lo;
    }
    return;
  }

  const int b = blockIdx.x;
  const int lane = tid & 63, w = tid >> 6;
  const float* scores = pred + (size_t)b * 3 * HW;  // channel 0 of predict
  for (int i = tid; i < HW; i += 1024) keys[i] = map_key(scores[i]);
  if (tid == 0) { s_prefix = 0u; s_kth = KSEL; }
  __syncthreads();

  for (int shift = 24; shift >= 0; shift -= 8) {
    if (tid < 256) hist[tid] = 0u;
    __syncthreads();
    unsigned int pref = s_prefix;
    unsigned int maskhi = (shift == 24) ? 0u : (0xFFFFFFFFu << (shift + 8));
    for (int i = tid; i < HW; i += 1024) {
      unsigned int k = keys[i];
      if ((k & maskhi) == pref) atomicAdd(&hist[(k >> shift) & 0xFFu], 1u);
    }
    __syncthreads();
    if (tid < 64) {
      unsigned int b0 = hist[tid * 4], b1 = hist[tid * 4 + 1];
      unsigned int b2 = hist[tid * 4 + 2], b3 = hist[tid * 4 + 3];
      unsigned int kth = s_kth;
      unsigned int T = b0 + b1 + b2 + b3;
      #pragma unroll
      for (int off = 1; off < 64; off <<= 1) {
        unsigned int t = __shfl_down(T, off, 64);
        if (tid + off < 64) T += t;
      }
      unsigned int U = __shfl_down(T, 1, 64);
      if (tid == 63) U = 0u;
      unsigned int s3 = b3 + U, s2 = b2 + s3, s1 = b1 + s2, s0 = b0 + s1;
      if (s0 >= kth && s1 < kth) { s_prefix = pref | ((unsigned)(4 * tid + 0) << shift); s_kth = kth - s1; }
      if (s1 >= kth && s2 < kth) { s_prefix = pref | ((unsigned)(4 * tid + 1) << shift); s_kth = kth - s2; }
      if (s2 >= kth && s3 < kth) { s_prefix = pref | ((unsigned)(4 * tid + 2) << shift); s_kth = kth - s3; }
      if (s3 >= kth && U  < kth) { s_prefix = pref | ((unsigned)(4 * tid + 3) << shift); s_kth = kth - U; }
    }
    __syncthreads();
  }
  const unsigned int thresh = s_prefix;

  unsigned int local[8];
  unsigned int sum = 0;
  #pragma unroll
  for (int e = 0; e < 8; ++e) {
    int i = tid * 8 + e;
    unsigned int p = 0;
    if (i < HW) {
      unsigned int ky = keys[i];
      if (ky > thresh) p = 1u;
      else if (ky == thresh) p = (1u << 16);
    }
    local[e] = p; sum += p;
  }
  __syncthreads();   // keys dead — overlay
  short* pos_of  = (short*)keys;
  int*   s_idx_sh = (int*)((char*)keys + 15000);
  for (int i = tid; i < HW; i += 1024) pos_of[i] = -1;

  unsigned int inc = sum;
  #pragma unroll
  for (int off = 1; off < 64; off <<= 1) {
    unsigned int t = __shfl_up(inc, off, 64);
    if (lane >= off) inc += t;
  }
  if (lane == 63) partials[w] = inc;
  __syncthreads();
  if (tid < 16) {
    unsigned int v = partials[tid];
    #pragma unroll
    for (int off = 1; off < 16; off <<= 1) {
      unsigned int t = __shfl_up(v, off, 64);
      if (tid >= off) v += t;
    }
    partials[tid] = v;
  }
  __syncthreads();
  unsigned int total = partials[15];
  unsigned int run = (w ? partials[w - 1] : 0u) + inc - sum;
  unsigned int ties = (unsigned int)KSEL - (total & 0xFFFFu);
  #pragma unroll
  for (int e = 0; e < 8; ++e) {
    int i = tid * 8 + e;
    unsigned int p = local[e];
    unsigned int gt_pref = run & 0xFFFFu;
    unsigned int eq_pref = run >> 16;
    bool sel = (p & 1u) || (((p >> 16) != 0u) && eq_pref < ties);
    if (sel) {
      unsigned int pos = gt_pref + (eq_pref < ties ? eq_pref : ties);
      off_ws[b * KSEL + pos] = (i % H_DIM) * W_DIM + i / H_DIM;  // gather quirk
      out_idx[b * KSEL + pos] = (float)i;
      s_idx_sh[pos] = i;
      pos_of[i] = (short)pos;
    }
    run += p;
  }
  __syncthreads();

  for (int i = tid; i < KSEL; i += 1024) {
    int q = s_idx_sh[i];
    int py = q / W_DIM, px = q % W_DIM;
    unsigned short tmp[9];
    int c = 0;
    #pragma unroll
    for (int dy = -1; dy <= 1; ++dy) {
      int y = py + dy;
      if ((unsigned)y >= (unsigned)H_DIM) continue;
      #pragma unroll
      for (int dx = -1; dx <= 1; ++dx) {
        int x = px + dx;
        if ((unsigned)x >= (unsigned)W_DIM) continue;
        short p = pos_of[y * W_DIM + x];
        if (p >= 0) tmp[c++] = (unsigned short)p;
      }
    }
    #pragma unroll
    for (int t = 0; t < 9; ++t)
      nbr[(size_t)(b * KSEL + i) * 9 + t] = (t < c) ? tmp[t] : (unsigned short)0;
    cnt[b * KSEL + i] = (unsigned char)c;
  }
}

// K2b: gather+clip via LDS plane staging; emits bf16 hi/lo split planes
// NFT_hi/NFT_lo [c][n] (ushort) for the MFMA GEMM. Half the write traffic
// of fp32.
__global__ __launch_bounds__(512) void gather_kernel(
    const float* __restrict__ feat, const int* __restrict__ off_ws,
    unsigned short* __restrict__ nft_hi, unsigned short* __restrict__ nft_lo)
{
  __shared__ __align__(16) float s_plane[HW];
  const int b = blockIdx.y;
  const int c = blockIdx.x;
  const int tid = threadIdx.x;
  const float4* p4 = (const float4*)(feat + ((size_t)b * CIN + c) * HW);
  float4* sp4 = (float4*)s_plane;
  #pragma unroll
  for (int i = tid; i < HW / 4; i += 512)
    sp4[i] = p4[i];
  __syncthreads();
  if (tid < KSEL / 4) {
    const uint4* o4 = (const uint4*)off_ws + (size_t)b * (KSEL / 4);
    uint4 o = o4[tid];
    float v0 = fminf(fmaxf(s_plane[o.x], 0.f), 6.f);
    float v1 = fminf(fmaxf(s_plane[o.y], 0.f), 6.f);
    float v2 = fminf(fmaxf(s_plane[o.z], 0.f), 6.f);
    float v3 = fminf(fmaxf(s_plane[o.w], 0.f), 6.f);
    ushort4 h, l;
    h.x = bf16_rne(v0); l.x = bf16_rne(v0 - bf16_to_f(h.x));
    h.y = bf16_rne(v1); l.y = bf16_rne(v1 - bf16_to_f(h.y));
    h.z = bf16_rne(v2); l.z = bf16_rne(v2 - bf16_to_f(h.z));
    h.w = bf16_rne(v3); l.w = bf16_rne(v3 - bf16_to_f(h.w));
    size_t row = ((size_t)b * CIN + c) * KSEL;
    ((ushort4*)&nft_hi[row])[tid] = h;
    ((ushort4*)&nft_lo[row])[tid] = l;
  }
}

// K3: G[2000x128] = clip(NF)[2000x512] @ w1 via bf16 MFMA, split-precision:
// a*w ~= ahi*whi + ahi*wlo + alo*whi (3 mfma_f32_32x32x16_bf16). 64-row x
// 128-col block tile, 4 waves: wave (wr,wc) owns rows wr*32+[0,32) and cols
// wc*64+[0,64) (two 32x32 tiles). Verified layouts: A[m=lane&31][k=q*8+j],
// B[k][n=lane&31] same; C/D col=lane&31, row=(reg&3)+8*(reg>>2)+4*q.
__global__ __launch_bounds__(256) void gemm1_mfma(
    const unsigned short* __restrict__ nft_hi,
    const unsigned short* __restrict__ nft_lo,
    const unsigned short* __restrict__ w1t_hi,
    const unsigned short* __restrict__ w1t_lo,
    float* __restrict__ G)
{
  __shared__ unsigned short a_hi[64][20], a_lo[64][20];   // 40 B rows: 2-way free
  __shared__ unsigned short b_hi[128][20], b_lo[128][20];
  const int b = blockIdx.y;
  const int n0 = blockIdx.x * 64;
  const int tid = threadIdx.x;
  const int lane = tid & 63, w = tid >> 6;
  const int wr = w & 1, wc = w >> 1;
  const int q = lane >> 5, m = lane & 31;
  v16f acc0, acc1;
  #pragma unroll
  for (int i = 0; i < 16; ++i) { acc0[i] = 0.f; acc1[i] = 0.f; }
  const unsigned short* nh = nft_hi + (size_t)b * CIN * KSEL;
  const unsigned short* nl = nft_lo + (size_t)b * CIN * KSEL;
  const int an = wr * 32 + m;
  const int f0 = wc * 64 + m;

  for (int k0 = 0; k0 < CIN; k0 += 16) {
    // stage A: 64 n x 16 k; thread: n = tid&63, k = (tid>>6)*4 + j
    {
      int n = tid & 63, ks = (tid >> 6) * 4;
      #pragma unroll
      for (int j = 0; j < 4; ++j) {
        int k = ks + j;
        size_t gi = (size_t)(k0 + k) * KSEL + n0 + n;
        a_hi[n][k] = nh[gi];
        a_lo[n][k] = nl[gi];
      }
    }
    // stage B: 128 f x 16 k from w1t[f][k]; thread: f = tid&127, kh = tid>>7
    {
      int f = tid & 127, kh = tid >> 7;
      const ushort4* sh = (const ushort4*)&w1t_hi[(size_t)f * CIN + k0 + kh * 8];
      const ushort4* sl = (const ushort4*)&w1t_lo[(size_t)f * CIN + k0 + kh * 8];
      ushort4 h0 = sh[0], h1 = sh[1], l0 = sl[0], l1 = sl[1];
      *(ushort4*)&b_hi[f][kh * 8]     = h0;
      *(ushort4*)&b_hi[f][kh * 8 + 4] = h1;
      *(ushort4*)&b_lo[f][kh * 8]     = l0;
      *(ushort4*)&b_lo[f][kh * 8 + 4] = l1;
    }
    __syncthreads();
    v4s ah0 = *(const v4s*)&a_hi[an][q * 8];
    v4s ah1 = *(const v4s*)&a_hi[an][q * 8 + 4];
    v4s al0 = *(const v4s*)&a_lo[an][q * 8];
    v4s al1 = *(const v4s*)&a_lo[an][q * 8 + 4];
    v8s av_hi = __builtin_shufflevector(ah0, ah1, 0, 1, 2, 3, 4, 5, 6, 7);
    v8s av_lo = __builtin_shufflevector(al0, al1, 0, 1, 2, 3, 4, 5, 6, 7);
    {
      v4s bh0 = *(const v4s*)&b_hi[f0][q * 8];
      v4s bh1 = *(const v4s*)&b_hi[f0][q * 8 + 4];
      v4s bl0 = *(const v4s*)&b_lo[f0][q * 8];
      v4s bl1 = *(const v4s*)&b_lo[f0][q * 8 + 4];
      v8s bv_hi = __builtin_shufflevector(bh0, bh1, 0, 1, 2, 3, 4, 5, 6, 7);
      v8s bv_lo = __builtin_shufflevector(bl0, bl1, 0, 1, 2, 3, 4, 5, 6, 7);
      acc0 = __builtin_amdgcn_mfma_f32_32x32x16_bf16(av_hi, bv_hi, acc0, 0, 0, 0);
      acc0 = __builtin_amdgcn_mfma_f32_32x32x16_bf16(av_hi, bv_lo, acc0, 0, 0, 0);
      acc0 = __builtin_amdgcn_mfma_f32_32x32x16_bf16(av_lo, bv_hi, acc0, 0, 0, 0);
    }
    {
      v4s bh0 = *(const v4s*)&b_hi[f0 + 32][q * 8];
      v4s bh1 = *(const v4s*)&b_hi[f0 + 32][q * 8 + 4];
      v4s bl0 = *(const v4s*)&b_lo[f0 + 32][q * 8];
      v4s bl1 = *(const v4s*)&b_lo[f0 + 32][q * 8 + 4];
      v8s bv_hi = __builtin_shufflevector(bh0, bh1, 0, 1, 2, 3, 4, 5, 6, 7);
      v8s bv_lo = __builtin_shufflevector(bl0, bl1, 0, 1, 2, 3, 4, 5, 6, 7);
      acc1 = __builtin_amdgcn_mfma_f32_32x32x16_bf16(av_hi, bv_hi, acc1, 0, 0, 0);
      acc1 = __builtin_amdgcn_mfma_f32_32x32x16_bf16(av_hi, bv_lo, acc1, 0, 0, 0);
      acc1 = __builtin_amdgcn_mfma_f32_32x32x16_bf16(av_lo, bv_hi, acc1, 0, 0, 0);
    }
    __syncthreads();
  }
  float* ob = G + (size_t)b * KSEL * FDIM;
  #pragma unroll
  for (int reg = 0; reg < 16; ++reg) {
    int row = n0 + wr * 32 + (reg & 3) + 8 * (reg >> 2) + 4 * q;
    if (row < KSEL) {
      ob[(size_t)row * FDIM + f0]      = acc0[reg];
      ob[(size_t)row * FDIM + f0 + 32] = acc1[reg];
    }
  }
}

// K5: Hm[2000x128] = x1 @ w2 (vector fp32; 0.5 GFLOP)
__global__ __launch_bounds__(256) void gemm2_kernel(
    const float* __restrict__ in, const float* __restrict__ wmat,
    float* __restrict__ out)
{
  __shared__ __align__(16) float a_lds[32][36];
  __shared__ __align__(16) float w_lds[32][128];
  const int b = blockIdx.y;
  const int n0 = blockIdx.x * 32;
  const int tid = threadIdx.x;
  const int tf = tid & 31, tr = tid >> 5;
  float acc[4][4] = {{0.f}};
  const float* fb = in + (size_t)b * KSEL * FDIM;
  for (int cc = 0; cc < FDIM; cc += 32) {
    const float4* w4 = (const float4*)(wmat + cc * 128);
    #pragma unroll
    for (int e = tid; e < 1024; e += 256) {
      int c = e >> 5, f4 = e & 31;
      ((float4*)&w_lds[c][0])[f4] = w4[e];
    }
    {
      int n = tid >> 3, c4 = tid & 7;
      float4 v = *(const float4*)&fb[(size_t)(n0 + n) * FDIM + cc + c4 * 4];
      a_lds[c4 * 4 + 0][n] = v.x;
      a_lds[c4 * 4 + 1][n] = v.y;
      a_lds[c4 * 4 + 2][n] = v.z;
      a_lds[c4 * 4 + 3][n] = v.w;
    }
    __syncthreads();
    #pragma unroll
    for (int c = 0; c < 32; ++c) {
      float4 av = *(const float4*)&a_lds[c][tr * 4];
      float4 wv = *(const float4*)&w_lds[c][tf * 4];
      acc[0][0] += av.x * wv.x; acc[0][1] += av.x * wv.y; acc[0][2] += av.x * wv.z; acc[0][3] += av.x * wv.w;
      acc[1][0] += av.y * wv.x; acc[1][1] += av.y * wv.y; acc[1][2] += av.y * wv.z; acc[1][3] += av.y * wv.w;
      acc[2][0] += av.z * wv.x; acc[2][1] += av.z * wv.y; acc[2][2] += av.z * wv.z; acc[2][3] += av.z * wv.w;
      acc[3][0] += av.w * wv.x; acc[3][1] += av.w * wv.y; acc[3][2] += av.w * wv.z; acc[3][3] += av.w * wv.w;
    }
    __syncthreads();
  }
  #pragma unroll
  for (int r = 0; r < 4; ++r) {
    int row = n0 + tr * 4 + r;
    if (row < KSEL) {
      float4 v = make_float4(acc[r][0], acc[r][1], acc[r][2], acc[r][3]);
      *(float4*)&out[((size_t)(b * KSEL + row)) * FDIM + tf * 4] = v;
    }
  }
}

// K4: x1[i] = b1[i] + sum_{j in nbr(i)} G[j]; 9 unconditional loads, masked.
__global__ __launch_bounds__(256) void x1_kernel(
    const float* __restrict__ G, const float* __restrict__ b1,
    const unsigned short* __restrict__ nbr, const unsigned char* __restrict__ cnt,
    float* __restrict__ x1)
{
  const int g = threadIdx.x >> 5, lane = threadIdx.x & 31;
  const int node = blockIdx.x * 8 + g;
  const int bb = blockIdx.y;
  const size_t bi = (size_t)bb * KSEL + node;
  const unsigned short* nb = nbr + bi * 9;
  unsigned short idx[9];
  #pragma unroll
  for (int t = 0; t < 9; ++t) idx[t] = nb[t];
  const int c = cnt[bi];
  const float4* G4 = (const float4*)G + (size_t)bb * KSEL * 32;
  float4 v[9];
  #pragma unroll
  for (int t = 0; t < 9; ++t) v[t] = G4[(size_t)idx[t] * 32 + lane];
  float4 acc = ((const float4*)b1)[node * 32 + lane];
  #pragma unroll
  for (int t = 0; t < 9; ++t) {
    float m = (t < c) ? 1.f : 0.f;
    acc.x = fmaf(v[t].x, m, acc.x);
    acc.y = fmaf(v[t].y, m, acc.y);
    acc.z = fmaf(v[t].z, m, acc.z);
    acc.w = fmaf(v[t].w, m, acc.w);
  }
  ((float4*)x1)[bi * 32 + lane] = acc;
}

// K6: out[i] = tanh(b2[i] + x1[i] + sum_{j in nbr(i)} H[j])
__global__ __launch_bounds__(256) void out_kernel(
    const float* __restrict__ Hm, const float* __restrict__ x1,
    const float* __restrict__ b2,
    const unsigned short* __restrict__ nbr, const unsigned char* __restrict__ cnt,
    float* __restrict__ out)
{
  const int g = threadIdx.x >> 5, lane = threadIdx.x & 31;
  const int node = blockIdx.x * 8 + g;
  const int bb = blockIdx.y;
  const size_t bi = (size_t)bb * KSEL + node;
  const unsigned short* nb = nbr + bi * 9;
  unsigned short idx[9];
  #pragma unroll
  for (int t = 0; t < 9; ++t) idx[t] = nb[t];
  const int c = cnt[bi];
  const float4* H4 = (const float4*)Hm + (size_t)bb * KSEL * 32;
  float4 v[9];
  #pragma unroll
  for (int t = 0; t < 9; ++t) v[t] = H4[(size_t)idx[t] * 32 + lane];
  float4 acc = ((const float4*)b2)[node * 32 + lane];
  float4 xv = ((const float4*)x1)[bi * 32 + lane];
  acc.x += xv.x; acc.y += xv.y; acc.z += xv.z; acc.w += xv.w;
  #pragma unroll
  for (int t = 0; t < 9; ++t) {
    float m = (t < c) ? 1.f : 0.f;
    acc.x = fmaf(v[t].x, m, acc.x);
    acc.y = fmaf(v[t].y, m, acc.y);
    acc.z = fmaf(v[t].z, m, acc.z);
    acc.w = fmaf(v[t].w, m, acc.w);
  }
  float4 r;
  r.x = fast_tanh(acc.x); r.y = fast_tanh(acc.y);
  r.z = fast_tanh(acc.z); r.w = fast_tanh(acc.w);
  ((float4*)out)[bi * 32 + lane] = r;
}

extern "C" void kernel_launch(void* const* d_in, const int* in_sizes, int n_in,
                              void* d_out, int out_size, void* d_ws, size_t ws_size,
                              hipStream_t stream) {
  const float* feat = (const float*)d_in[0];
  const float* pred = (const float*)d_in[1];
  const float* w1   = (const float*)d_in[2];
  const float* b1   = (const float*)d_in[3];
  const float* w2   = (const float*)d_in[4];
  const float* b2   = (const float*)d_in[5];
  float* out0 = (float*)d_out;                              // (8,2000,128) fp32
  float* out_idx = out0 + (size_t)BATCH * KSEL * FDIM;      // (8,2000) as fp32

  // workspace layout (256B-aligned). NFT hi/lo dead after gemm1 -> x1/Hm
  // overlay them. gemm1's last tile reads <=94 B past NFT_lo end: slack kept.
  char* ws = (char*)d_ws;
  int*            off_ws = (int*)(ws + 0);                  //  64000 B
  unsigned short* nbr    = (unsigned short*)(ws + 64256);   // 288000 B
  unsigned char*  cnt    = (unsigned char*)(ws + 352512);   //  16000 B
  float*          G      = (float*)(ws + 368640);           // 8,192,000 B
  char*           R      = ws + 8560640;                    // overlay region
  unsigned short* nft_hi = (unsigned short*)R;              // 16,384,000 B
  unsigned short* nft_lo = (unsigned short*)(R + 16384000); // 16,384,000 B
  unsigned short* w1t_hi = (unsigned short*)(R + 32768256); // 131,072 B (+slack)
  unsigned short* w1t_lo = (unsigned short*)(R + 32899328); // 131,072 B
  float*          x1     = (float*)R;                       // after gemm1
  float*          Hm     = (float*)(R + 8388608);           // after gemm1

  topk_nbr_kernel<<<BATCH + 8, 1024, 0, stream>>>(pred, w1, off_ws, out_idx,
                                                  nbr, cnt, w1t_hi, w1t_lo);
  gather_kernel<<<dim3(CIN, BATCH), 512, 0, stream>>>(feat, off_ws, nft_hi, nft_lo);
  gemm1_mfma<<<dim3(32, BATCH), 256, 0, stream>>>(nft_hi, nft_lo, w1t_hi, w1t_lo, G);
  x1_kernel<<<dim3(KSEL / 8, BATCH), 256, 0, stream>>>(G, b1, nbr, cnt, x1);
  gemm2_kernel<<<dim3(63, BATCH), 256, 0, stream>>>(x1, w2, Hm);
  out_kernel<<<dim3(KSEL / 8, BATCH), 256, 0, stream>>>(Hm, x1, b2, nbr, cnt, out0);
}

// Round 8
// 262.006 us; speedup vs baseline: 1.7729x; 1.0230x over previous
//
#include <hip/hip_runtime.h>
#include <cmath>

#define H_DIM 75
#define W_DIM 100
#define HW 7500
#define KSEL 2000
#define BATCH 8
#define CIN 512
#define FDIM 128

typedef short v4s __attribute__((ext_vector_type(4)));
typedef short v8s __attribute__((ext_vector_type(8)));
typedef float v16f __attribute__((ext_vector_type(16)));

__device__ __forceinline__ unsigned int map_key(float f) {
  unsigned int u = __float_as_uint(f);
  return (u & 0x80000000u) ? ~u : (u | 0x80000000u);
}

__device__ __forceinline__ float fast_tanh(float x) {
  float e = __expf(2.0f * x);
  return 1.0f - 2.0f * __builtin_amdgcn_rcpf(e + 1.0f);
}

__device__ __forceinline__ unsigned short bf16_rne(float v) {
  unsigned int u = __float_as_uint(v);
  unsigned int r = u + 0x7FFFu + ((u >> 16) & 1u);
  return (unsigned short)(r >> 16);
}
__device__ __forceinline__ float bf16_to_f(unsigned short h) {
  return __uint_as_float(((unsigned int)h) << 16);
}

// K1 (fused): blocks 0..7 per-batch top-K (radix select with per-wave
// privatized histograms -> low LDS-atomic contention) + packed scan (exact
// lax.top_k+sort semantics) + neighbor lists. Blocks 8..15 split w1 AND w2
// into transposed bf16 hi/lo planes for the MFMA GEMMs.
__global__ __launch_bounds__(1024) void topk_nbr_kernel(
    const float* __restrict__ pred, const float* __restrict__ w1,
    const float* __restrict__ w2,
    int* __restrict__ off_ws, float* __restrict__ out_idx,
    unsigned short* __restrict__ nbr, unsigned char* __restrict__ cnt,
    unsigned short* __restrict__ w1t_hi, unsigned short* __restrict__ w1t_lo,
    unsigned short* __restrict__ w2t_hi, unsigned short* __restrict__ w2t_lo)
{
  __shared__ unsigned int keys[HW];        // 30 KB; reused: pos_of + s_idx
  __shared__ unsigned int whist[16 * 256]; // per-wave histograms, 16 KB
  __shared__ unsigned int hist[256];
  __shared__ unsigned int partials[16];
  __shared__ unsigned int s_prefix, s_kth;
  const int tid = threadIdx.x;

  if (blockIdx.x >= BATCH) {               // weight split: 8 blocks x 1024 thr
    int base = (blockIdx.x - BATCH) * 1024 + tid;
    for (int e = base; e < CIN * FDIM + FDIM * FDIM; e += 8 * 1024) {
      if (e < CIN * FDIM) {
        int k = e & (CIN - 1), f = e >> 9;   // k-inner: coalesced writes
        float v = w1[k * FDIM + f];
        unsigned short hi = bf16_rne(v);
        unsigned short lo = bf16_rne(v - bf16_to_f(hi));
        w1t_hi[(size_t)f * CIN + k] = hi;
        w1t_lo[(size_t)f * CIN + k] = lo;
      } else {
        int e2 = e - CIN * FDIM;
        int k = e2 & (FDIM - 1), f = e2 >> 7;
        float v = w2[k * FDIM + f];
        unsigned short hi = bf16_rne(v);
        unsigned short lo = bf16_rne(v - bf16_to_f(hi));
        w2t_hi[(size_t)f * FDIM + k] = hi;
        w2t_lo[(size_t)f * FDIM + k] = lo;
      }
    }
    return;
  }

  const int b = blockIdx.x;
  const int lane = tid & 63, w = tid >> 6;
  const float* scores = pred + (size_t)b * 3 * HW;  // channel 0 of predict
  for (int i = tid; i < HW; i += 1024) keys[i] = map_key(scores[i]);
  if (tid == 0) { s_prefix = 0u; s_kth = KSEL; }
  __syncthreads();

  // radix select, MSB-first, 8 bits/round
  for (int shift = 24; shift >= 0; shift -= 8) {
    for (int i = tid; i < 16 * 256; i += 1024) whist[i] = 0u;
    __syncthreads();
    unsigned int pref = s_prefix;
    unsigned int maskhi = (shift == 24) ? 0u : (0xFFFFFFFFu << (shift + 8));
    for (int i = tid; i < HW; i += 1024) {
      unsigned int k = keys[i];
      if ((k & maskhi) == pref)
        atomicAdd(&whist[w * 256 + ((k >> shift) & 0xFFu)], 1u);
    }
    __syncthreads();
    if (tid < 256) {
      unsigned int s = 0;
      #pragma unroll
      for (int ww = 0; ww < 16; ++ww) s += whist[ww * 256 + tid];
      hist[tid] = s;
    }
    __syncthreads();
    if (tid < 64) {
      unsigned int b0 = hist[tid * 4], b1 = hist[tid * 4 + 1];
      unsigned int b2 = hist[tid * 4 + 2], b3 = hist[tid * 4 + 3];
      unsigned int kth = s_kth;
      unsigned int T = b0 + b1 + b2 + b3;
      #pragma unroll
      for (int off = 1; off < 64; off <<= 1) {
        unsigned int t = __shfl_down(T, off, 64);
        if (tid + off < 64) T += t;         // inclusive suffix of lane totals
      }
      unsigned int U = __shfl_down(T, 1, 64);
      if (tid == 63) U = 0u;                // suffix strictly after this lane
      unsigned int s3 = b3 + U, s2 = b2 + s3, s1 = b1 + s2, s0 = b0 + s1;
      if (s0 >= kth && s1 < kth) { s_prefix = pref | ((unsigned)(4 * tid + 0) << shift); s_kth = kth - s1; }
      if (s1 >= kth && s2 < kth) { s_prefix = pref | ((unsigned)(4 * tid + 1) << shift); s_kth = kth - s2; }
      if (s2 >= kth && s3 < kth) { s_prefix = pref | ((unsigned)(4 * tid + 2) << shift); s_kth = kth - s3; }
      if (s3 >= kth && U  < kth) { s_prefix = pref | ((unsigned)(4 * tid + 3) << shift); s_kth = kth - U; }
    }
    __syncthreads();
  }
  const unsigned int thresh = s_prefix;

  // selection flags: gt in low 16 bits, eq in high 16, packed
  unsigned int local[8];
  unsigned int sum = 0;
  #pragma unroll
  for (int e = 0; e < 8; ++e) {
    int i = tid * 8 + e;
    unsigned int p = 0;
    if (i < HW) {
      unsigned int ky = keys[i];
      if (ky > thresh) p = 1u;
      else if (ky == thresh) p = (1u << 16);
    }
    local[e] = p; sum += p;
  }
  __syncthreads();   // keys dead — overlay
  short* pos_of  = (short*)keys;
  int*   s_idx_sh = (int*)((char*)keys + 15000);
  for (int i = tid; i < HW; i += 1024) pos_of[i] = -1;

  // two-level exclusive prefix scan
  unsigned int inc = sum;
  #pragma unroll
  for (int off = 1; off < 64; off <<= 1) {
    unsigned int t = __shfl_up(inc, off, 64);
    if (lane >= off) inc += t;
  }
  if (lane == 63) partials[w] = inc;
  __syncthreads();
  if (tid < 16) {
    unsigned int v = partials[tid];
    #pragma unroll
    for (int off = 1; off < 16; off <<= 1) {
      unsigned int t = __shfl_up(v, off, 64);
      if (tid >= off) v += t;
    }
    partials[tid] = v;
  }
  __syncthreads();
  unsigned int total = partials[15];
  unsigned int run = (w ? partials[w - 1] : 0u) + inc - sum;
  unsigned int ties = (unsigned int)KSEL - (total & 0xFFFFu);
  #pragma unroll
  for (int e = 0; e < 8; ++e) {
    int i = tid * 8 + e;
    unsigned int p = local[e];
    unsigned int gt_pref = run & 0xFFFFu;
    unsigned int eq_pref = run >> 16;
    bool sel = (p & 1u) || (((p >> 16) != 0u) && eq_pref < ties);
    if (sel) {
      unsigned int pos = gt_pref + (eq_pref < ties ? eq_pref : ties);
      off_ws[b * KSEL + pos] = (i % H_DIM) * W_DIM + i / H_DIM;  // gather quirk
      out_idx[b * KSEL + pos] = (float)i;
      s_idx_sh[pos] = i;
      pos_of[i] = (short)pos;
    }
    run += p;
  }
  __syncthreads();

  // neighbor lists; rows padded to 9 (pad=0) so consumers load unconditionally
  for (int i = tid; i < KSEL; i += 1024) {
    int q = s_idx_sh[i];
    int py = q / W_DIM, px = q % W_DIM;
    unsigned short tmp[9];
    int c = 0;
    #pragma unroll
    for (int dy = -1; dy <= 1; ++dy) {
      int y = py + dy;
      if ((unsigned)y >= (unsigned)H_DIM) continue;
      #pragma unroll
      for (int dx = -1; dx <= 1; ++dx) {
        int x = px + dx;
        if ((unsigned)x >= (unsigned)W_DIM) continue;
        short p = pos_of[y * W_DIM + x];
        if (p >= 0) tmp[c++] = (unsigned short)p;
      }
    }
    #pragma unroll
    for (int t = 0; t < 9; ++t)
      nbr[(size_t)(b * KSEL + i) * 9 + t] = (t < c) ? tmp[t] : (unsigned short)0;
    cnt[b * KSEL + i] = (unsigned char)c;
  }
}

// K2b: gather+clip via LDS plane staging; emits bf16 hi/lo planes [c][n].
__global__ __launch_bounds__(512) void gather_kernel(
    const float* __restrict__ feat, const int* __restrict__ off_ws,
    unsigned short* __restrict__ nft_hi, unsigned short* __restrict__ nft_lo)
{
  __shared__ __align__(16) float s_plane[HW];
  const int b = blockIdx.y;
  const int c = blockIdx.x;
  const int tid = threadIdx.x;
  const float4* p4 = (const float4*)(feat + ((size_t)b * CIN + c) * HW);
  float4* sp4 = (float4*)s_plane;
  #pragma unroll
  for (int i = tid; i < HW / 4; i += 512)
    sp4[i] = p4[i];
  __syncthreads();
  if (tid < KSEL / 4) {
    const uint4* o4 = (const uint4*)off_ws + (size_t)b * (KSEL / 4);
    uint4 o = o4[tid];
    float v0 = fminf(fmaxf(s_plane[o.x], 0.f), 6.f);
    float v1 = fminf(fmaxf(s_plane[o.y], 0.f), 6.f);
    float v2 = fminf(fmaxf(s_plane[o.z], 0.f), 6.f);
    float v3 = fminf(fmaxf(s_plane[o.w], 0.f), 6.f);
    ushort4 h, l;
    h.x = bf16_rne(v0); l.x = bf16_rne(v0 - bf16_to_f(h.x));
    h.y = bf16_rne(v1); l.y = bf16_rne(v1 - bf16_to_f(h.y));
    h.z = bf16_rne(v2); l.z = bf16_rne(v2 - bf16_to_f(h.z));
    h.w = bf16_rne(v3); l.w = bf16_rne(v3 - bf16_to_f(h.w));
    size_t row = ((size_t)b * CIN + c) * KSEL;
    ((ushort4*)&nft_hi[row])[tid] = h;
    ((ushort4*)&nft_lo[row])[tid] = l;
  }
}

// K3: G = clip(NF) @ w1, split-precision bf16 MFMA (hi*hi + hi*lo + lo*hi).
// 64x128 tile, 4 waves. A staged in double-buffered LDS (1 barrier/chunk);
// B read directly from L2-resident w1t (16 B contiguous per fragment).
__global__ __launch_bounds__(256) void gemm1_mfma(
    const unsigned short* __restrict__ nft_hi,
    const unsigned short* __restrict__ nft_lo,
    const unsigned short* __restrict__ w1t_hi,
    const unsigned short* __restrict__ w1t_lo,
    float* __restrict__ G)
{
  __shared__ unsigned short a_hi[2][64][20], a_lo[2][64][20];  // 10 KB
  const int b = blockIdx.y;
  const int n0 = blockIdx.x * 64;
  const int tid = threadIdx.x;
  const int lane = tid & 63, w = tid >> 6;
  const int wr = w & 1, wc = w >> 1;
  const int q = lane >> 5, m = lane & 31;
  v16f acc0, acc1;
  #pragma unroll
  for (int i = 0; i < 16; ++i) { acc0[i] = 0.f; acc1[i] = 0.f; }
  const unsigned short* nh = nft_hi + (size_t)b * CIN * KSEL;
  const unsigned short* nl = nft_lo + (size_t)b * CIN * KSEL;
  const int an = wr * 32 + m;
  const int f0 = wc * 64 + m;
  const int n_st = tid & 63, ks = (tid >> 6) * 4;

  #pragma unroll
  for (int j = 0; j < 4; ++j) {               // prologue: stage chunk 0
    size_t gi = (size_t)(ks + j) * KSEL + n0 + n_st;
    a_hi[0][n_st][ks + j] = nh[gi];
    a_lo[0][n_st][ks + j] = nl[gi];
  }
  __syncthreads();

  for (int k0 = 0; k0 < CIN; k0 += 16) {
    const int p = (k0 >> 4) & 1;
    if (k0 + 16 < CIN) {                      // stage next into other buffer
      #pragma unroll
      for (int j = 0; j < 4; ++j) {
        size_t gi = (size_t)(k0 + 16 + ks + j) * KSEL + n0 + n_st;
        a_hi[p ^ 1][n_st][ks + j] = nh[gi];
        a_lo[p ^ 1][n_st][ks + j] = nl[gi];
      }
    }
    v4s ah0 = *(const v4s*)&a_hi[p][an][q * 8];
    v4s ah1 = *(const v4s*)&a_hi[p][an][q * 8 + 4];
    v4s al0 = *(const v4s*)&a_lo[p][an][q * 8];
    v4s al1 = *(const v4s*)&a_lo[p][an][q * 8 + 4];
    v8s avh = __builtin_shufflevector(ah0, ah1, 0, 1, 2, 3, 4, 5, 6, 7);
    v8s avl = __builtin_shufflevector(al0, al1, 0, 1, 2, 3, 4, 5, 6, 7);
    v8s b0h = *(const v8s*)&w1t_hi[(size_t)f0 * CIN + k0 + q * 8];
    v8s b0l = *(const v8s*)&w1t_lo[(size_t)f0 * CIN + k0 + q * 8];
    v8s b1h = *(const v8s*)&w1t_hi[(size_t)(f0 + 32) * CIN + k0 + q * 8];
    v8s b1l = *(const v8s*)&w1t_lo[(size_t)(f0 + 32) * CIN + k0 + q * 8];
    acc0 = __builtin_amdgcn_mfma_f32_32x32x16_bf16(avh, b0h, acc0, 0, 0, 0);
    acc0 = __builtin_amdgcn_mfma_f32_32x32x16_bf16(avh, b0l, acc0, 0, 0, 0);
    acc0 = __builtin_amdgcn_mfma_f32_32x32x16_bf16(avl, b0h, acc0, 0, 0, 0);
    acc1 = __builtin_amdgcn_mfma_f32_32x32x16_bf16(avh, b1h, acc1, 0, 0, 0);
    acc1 = __builtin_amdgcn_mfma_f32_32x32x16_bf16(avh, b1l, acc1, 0, 0, 0);
    acc1 = __builtin_amdgcn_mfma_f32_32x32x16_bf16(avl, b1h, acc1, 0, 0, 0);
    __syncthreads();
  }
  float* ob = G + (size_t)b * KSEL * FDIM;
  #pragma unroll
  for (int reg = 0; reg < 16; ++reg) {
    int row = n0 + wr * 32 + (reg & 3) + 8 * (reg >> 2) + 4 * q;
    if (row < KSEL) {
      ob[(size_t)row * FDIM + f0]      = acc0[reg];
      ob[(size_t)row * FDIM + f0 + 32] = acc1[reg];
    }
  }
}

// K4: x1[i] = b1[i] + sum_{j in nbr(i)} G[j]; also emits bf16 hi/lo split of
// x1 for the LDS-free MFMA gemm2.
__global__ __launch_bounds__(256) void x1_kernel(
    const float* __restrict__ G, const float* __restrict__ b1,
    const unsigned short* __restrict__ nbr, const unsigned char* __restrict__ cnt,
    float* __restrict__ x1, unsigned short* __restrict__ x1h,
    unsigned short* __restrict__ x1l)
{
  const int g = threadIdx.x >> 5, lane = threadIdx.x & 31;
  const int node = blockIdx.x * 8 + g;
  const int bb = blockIdx.y;
  const size_t bi = (size_t)bb * KSEL + node;
  const unsigned short* nb = nbr + bi * 9;
  unsigned short idx[9];
  #pragma unroll
  for (int t = 0; t < 9; ++t) idx[t] = nb[t];
  const int c = cnt[bi];
  const float4* G4 = (const float4*)G + (size_t)bb * KSEL * 32;
  float4 v[9];
  #pragma unroll
  for (int t = 0; t < 9; ++t) v[t] = G4[(size_t)idx[t] * 32 + lane];
  float4 acc = ((const float4*)b1)[node * 32 + lane];
  #pragma unroll
  for (int t = 0; t < 9; ++t) {
    float mk = (t < c) ? 1.f : 0.f;
    acc.x = fmaf(v[t].x, mk, acc.x);
    acc.y = fmaf(v[t].y, mk, acc.y);
    acc.z = fmaf(v[t].z, mk, acc.z);
    acc.w = fmaf(v[t].w, mk, acc.w);
  }
  ((float4*)x1)[bi * 32 + lane] = acc;
  ushort4 h, l;
  h.x = bf16_rne(acc.x); l.x = bf16_rne(acc.x - bf16_to_f(h.x));
  h.y = bf16_rne(acc.y); l.y = bf16_rne(acc.y - bf16_to_f(h.y));
  h.z = bf16_rne(acc.z); l.z = bf16_rne(acc.z - bf16_to_f(h.z));
  h.w = bf16_rne(acc.w); l.w = bf16_rne(acc.w - bf16_to_f(h.w));
  ((ushort4*)x1h)[bi * 32 + lane] = h;
  ((ushort4*)x1l)[bi * 32 + lane] = l;
}

// K5: Hm = x1 @ w2 via split-precision bf16 MFMA. LDS-free, barrier-free:
// A fragments read directly from row-major x1h/x1l (16 B contiguous),
// B fragments from transposed w2t hi/lo (64 KB, L2-resident).
__global__ __launch_bounds__(256) void gemm2_mfma(
    const unsigned short* __restrict__ x1h,
    const unsigned short* __restrict__ x1l,
    const unsigned short* __restrict__ w2t_hi,
    const unsigned short* __restrict__ w2t_lo,
    float* __restrict__ Hm)
{
  const int b = blockIdx.y;
  const int n0 = blockIdx.x * 64;
  const int tid = threadIdx.x;
  const int lane = tid & 63, w = tid >> 6;
  const int wr = w & 1, wc = w >> 1;
  const int q = lane >> 5, m = lane & 31;
  int arow = n0 + wr * 32 + m;
  if (arow > KSEL - 1) arow = KSEL - 1;   // clamp: corrupt rows never stored
  const unsigned short* xh = x1h + ((size_t)b * KSEL + arow) * FDIM;
  const unsigned short* xl = x1l + ((size_t)b * KSEL + arow) * FDIM;
  const int f0 = wc * 64 + m;
  v16f acc0, acc1;
  #pragma unroll
  for (int i = 0; i < 16; ++i) { acc0[i] = 0.f; acc1[i] = 0.f; }
  #pragma unroll
  for (int k0 = 0; k0 < FDIM; k0 += 16) {
    v8s avh = *(const v8s*)&xh[k0 + q * 8];
    v8s avl = *(const v8s*)&xl[k0 + q * 8];
    v8s b0h = *(const v8s*)&w2t_hi[(size_t)f0 * FDIM + k0 + q * 8];
    v8s b0l = *(const v8s*)&w2t_lo[(size_t)f0 * FDIM + k0 + q * 8];
    v8s b1h = *(const v8s*)&w2t_hi[(size_t)(f0 + 32) * FDIM + k0 + q * 8];
    v8s b1l = *(const v8s*)&w2t_lo[(size_t)(f0 + 32) * FDIM + k0 + q * 8];
    acc0 = __builtin_amdgcn_mfma_f32_32x32x16_bf16(avh, b0h, acc0, 0, 0, 0);
    acc0 = __builtin_amdgcn_mfma_f32_32x32x16_bf16(avh, b0l, acc0, 0, 0, 0);
    acc0 = __builtin_amdgcn_mfma_f32_32x32x16_bf16(avl, b0h, acc0, 0, 0, 0);
    acc1 = __builtin_amdgcn_mfma_f32_32x32x16_bf16(avh, b1h, acc1, 0, 0, 0);
    acc1 = __builtin_amdgcn_mfma_f32_32x32x16_bf16(avh, b1l, acc1, 0, 0, 0);
    acc1 = __builtin_amdgcn_mfma_f32_32x32x16_bf16(avl, b1h, acc1, 0, 0, 0);
  }
  float* ob = Hm + (size_t)b * KSEL * FDIM;
  #pragma unroll
  for (int reg = 0; reg < 16; ++reg) {
    int row = n0 + wr * 32 + (reg & 3) + 8 * (reg >> 2) + 4 * q;
    if (row < KSEL) {
      ob[(size_t)row * FDIM + f0]      = acc0[reg];
      ob[(size_t)row * FDIM + f0 + 32] = acc1[reg];
    }
  }
}

// K6: out[i] = tanh(b2[i] + x1[i] + sum_{j in nbr(i)} H[j])
__global__ __launch_bounds__(256) void out_kernel(
    const float* __restrict__ Hm, const float* __restrict__ x1,
    const float* __restrict__ b2,
    const unsigned short* __restrict__ nbr, const unsigned char* __restrict__ cnt,
    float* __restrict__ out)
{
  const int g = threadIdx.x >> 5, lane = threadIdx.x & 31;
  const int node = blockIdx.x * 8 + g;
  const int bb = blockIdx.y;
  const size_t bi = (size_t)bb * KSEL + node;
  const unsigned short* nb = nbr + bi * 9;
  unsigned short idx[9];
  #pragma unroll
  for (int t = 0; t < 9; ++t) idx[t] = nb[t];
  const int c = cnt[bi];
  const float4* H4 = (const float4*)Hm + (size_t)bb * KSEL * 32;
  float4 v[9];
  #pragma unroll
  for (int t = 0; t < 9; ++t) v[t] = H4[(size_t)idx[t] * 32 + lane];
  float4 acc = ((const float4*)b2)[node * 32 + lane];
  float4 xv = ((const float4*)x1)[bi * 32 + lane];
  acc.x += xv.x; acc.y += xv.y; acc.z += xv.z; acc.w += xv.w;
  #pragma unroll
  for (int t = 0; t < 9; ++t) {
    float mk = (t < c) ? 1.f : 0.f;
    acc.x = fmaf(v[t].x, mk, acc.x);
    acc.y = fmaf(v[t].y, mk, acc.y);
    acc.z = fmaf(v[t].z, mk, acc.z);
    acc.w = fmaf(v[t].w, mk, acc.w);
  }
  float4 r;
  r.x = fast_tanh(acc.x); r.y = fast_tanh(acc.y);
  r.z = fast_tanh(acc.z); r.w = fast_tanh(acc.w);
  ((float4*)out)[bi * 32 + lane] = r;
}

extern "C" void kernel_launch(void* const* d_in, const int* in_sizes, int n_in,
                              void* d_out, int out_size, void* d_ws, size_t ws_size,
                              hipStream_t stream) {
  const float* feat = (const float*)d_in[0];
  const float* pred = (const float*)d_in[1];
  const float* w1   = (const float*)d_in[2];
  const float* b1   = (const float*)d_in[3];
  const float* w2   = (const float*)d_in[4];
  const float* b2   = (const float*)d_in[5];
  float* out0 = (float*)d_out;                              // (8,2000,128) fp32
  float* out_idx = out0 + (size_t)BATCH * KSEL * FDIM;      // (8,2000) as fp32

  // workspace layout (256B-aligned). Overlay region R: nft hi/lo live until
  // gemm1; x1/Hm/x1h/x1l live after. w2t lives outside R (read by gemm2).
  char* ws = (char*)d_ws;
  int*            off_ws = (int*)(ws + 0);                  //  64000 B
  unsigned short* nbr    = (unsigned short*)(ws + 64256);   // 288000 B
  unsigned char*  cnt    = (unsigned char*)(ws + 352512);   //  16000 B
  float*          G      = (float*)(ws + 368640);           // 8,192,000 B
  char*           R      = ws + 8560640;
  unsigned short* nft_hi = (unsigned short*)R;              // 16,384,000 B
  unsigned short* nft_lo = (unsigned short*)(R + 16384000); // 16,384,000 B
  unsigned short* w1t_hi = (unsigned short*)(R + 32768256); // 131,072 B (+slack)
  unsigned short* w1t_lo = (unsigned short*)(R + 32899328); // 131,072 B
  unsigned short* w2t_hi = (unsigned short*)(R + 33030656); //  32,768 B
  unsigned short* w2t_lo = (unsigned short*)(R + 33063424); //  32,768 B
  float*          x1     = (float*)R;                       // 8,192,000 B
  float*          Hm     = (float*)(R + 8388608);           // 8,192,000 B
  unsigned short* x1h    = (unsigned short*)(R + 16777216); // 4,096,000 B
  unsigned short* x1l    = (unsigned short*)(R + 20873472); // 4,096,000 B

  topk_nbr_kernel<<<BATCH + 8, 1024, 0, stream>>>(
      pred, w1, w2, off_ws, out_idx, nbr, cnt, w1t_hi, w1t_lo, w2t_hi, w2t_lo);
  gather_kernel<<<dim3(CIN, BATCH), 512, 0, stream>>>(feat, off_ws, nft_hi, nft_lo);
  gemm1_mfma<<<dim3(32, BATCH), 256, 0, stream>>>(nft_hi, nft_lo, w1t_hi, w1t_lo, G);
  x1_kernel<<<dim3(KSEL / 8, BATCH), 256, 0, stream>>>(G, b1, nbr, cnt, x1, x1h, x1l);
  gemm2_mfma<<<dim3(32, BATCH), 256, 0, stream>>>(x1h, x1l, w2t_hi, w2t_lo, Hm);
  out_kernel<<<dim3(KSEL / 8, BATCH), 256, 0, stream>>>(Hm, x1, b2, nbr, cnt, out0);
}